// Round 6
// baseline (523.821 us; speedup 1.0000x reference)
//
#include <hip/hip_runtime.h>

// MiniS4D: B=16, D=512, N=64 states, L=4096, C=8 chunks of S=512.
// Pipeline: k_params -> k_wcvt -> k_ucvt (u->bf16) -> k_hgemm (Vandermonde MFMA -> H)
//           -> k_kc (kernel tail, D on diagonal) -> k_seedpack -> k_conv (Toeplitz+seed MFMA)
//           -> k_tg (gelu + transpose -> yg (b,l,d)) -> k_gemm (GLU) -> k_final
// ws byte layout (153.6 MB):
//   [0)          params: p_ar,p_ai,p_wr,p_wi,p_dr,p_di,p_lr,p_li (8 x 131072)
//   [1048576)    pooled 32KB
//   [1081344)    wbf 1MB
//   [2129920)    UBF  u_bf bf16 67.1MB   (ALIAS: yg reuses this region after k_conv)
//   [69238784)   YRAW bf16 67.1MB        (ALIAS: Hbuf float2 33.55MB in first half)
//   [136347648)  seedB bf16 16.8MB
//   [153124864)  Kbuf bf16 0.52MB  -> end 153649152

#define UOFF_POOLED 1048576
#define UOFF_WBF    1081344
#define UOFF_UBF    2129920
#define UOFF_YRAW   69238784
#define UOFF_SEEDB  136347648
#define UOFF_KBUF   153124864

typedef __attribute__((ext_vector_type(8))) short short8;
typedef __attribute__((ext_vector_type(4))) float f32x4;
typedef __attribute__((ext_vector_type(2))) float f2;
typedef unsigned short ushort_t;
typedef unsigned int uint_t;

__device__ __forceinline__ ushort_t f2bf(float f) {
  uint_t u = __float_as_uint(f);
  u = (u + 0x7FFF + ((u >> 16) & 1)) >> 16;  // RNE
  return (ushort_t)u;
}
__device__ __forceinline__ float bf2f(ushort_t v) {
  return __uint_as_float(((uint_t)v) << 16);
}

// async global->LDS 16B: linear LDS dest (wave-uniform base + lane*16)
__device__ __forceinline__ void gload16(const ushort_t* g, ushort_t* l) {
  __builtin_amdgcn_global_load_lds(
      (const __attribute__((address_space(1))) void*)g,
      (__attribute__((address_space(3))) void*)l, 16, 0, 0);
}

// exp(dr*t) * cis(di*t)
__device__ __forceinline__ f2 cexp(float dr, float di, float t) {
  float e = expf(dr * t);
  float ph = di * t;
  return (f2){e * cosf(ph), e * sinf(ph)};
}

// ---- derived SSM params ----------------------------------------------------
__global__ void k_params(const float* __restrict__ log_dt,
                         const float* __restrict__ log_A_real,
                         const float* __restrict__ A_imag,
                         const float* __restrict__ B_re, const float* __restrict__ B_im,
                         const float* __restrict__ C_re, const float* __restrict__ C_im,
                         float* __restrict__ p_ar, float* __restrict__ p_ai,
                         float* __restrict__ p_wr, float* __restrict__ p_wi,
                         float* __restrict__ p_dr, float* __restrict__ p_di,
                         float* __restrict__ p_lr, float* __restrict__ p_li) {
  int i = blockIdx.x * blockDim.x + threadIdx.x;   // 0..32767, d = i>>6
  int d = i >> 6;
  float dt  = expf(log_dt[d]);
  float Are = -expf(log_A_real[i]);
  float Aim = A_imag[i];
  float dre = dt * Are, dim = dt * Aim;
  float em  = expf(dre);
  float abr = em * cosf(dim);
  float abi = em * sinf(dim);
  float nr = abr - 1.0f, ni = abi;
  float inv = 1.0f / (Are * Are + Aim * Aim);
  float br = (nr * Are + ni * Aim) * inv;
  float bi = (ni * Are - nr * Aim) * inv;
  float Br = B_re[i], Bi = B_im[i];
  float b2r = br * Br - bi * Bi;
  float b2i = br * Bi + bi * Br;
  float Cr = C_re[i], Ci = C_im[i];
  p_ar[i] = abr; p_ai[i] = abi;
  p_wr[i] = Cr * b2r - Ci * b2i;
  p_wi[i] = Cr * b2i + Ci * b2r;
  p_dr[i] = dre; p_di[i] = dim;
  float eL = expf(dre * 4096.0f);
  float phL = dim * 4096.0f;
  p_lr[i] = eL * cosf(phL);
  p_li[i] = eL * sinf(phL);
}

// ---- W_out fp32 -> bf16 -----------------------------------------------------
__global__ void k_wcvt(const float* __restrict__ w, ushort_t* __restrict__ wb, int n) {
  int i = blockIdx.x * blockDim.x + threadIdx.x;
  if (i < n) wb[i] = f2bf(w[i]);
}

// ---- u fp32 -> bf16 (8 elems/thread) ---------------------------------------
__global__ __launch_bounds__(256) void k_ucvt(const float* __restrict__ u,
                                              ushort_t* __restrict__ u_bf) {
  size_t i = (size_t)blockIdx.x * 256 + threadIdx.x;   // per 8 elems
  const float4* p = (const float4*)u + 2 * i;
  float4 a = p[0], b = p[1];
  uint4 v;
  v.x = (uint_t)f2bf(a.x) | ((uint_t)f2bf(a.y) << 16);
  v.y = (uint_t)f2bf(a.z) | ((uint_t)f2bf(a.w) << 16);
  v.z = (uint_t)f2bf(b.x) | ((uint_t)f2bf(b.y) << 16);
  v.w = (uint_t)f2bf(b.z) | ((uint_t)f2bf(b.w) << 16);
  ((uint4*)u_bf)[i] = v;
}

// ---- K1: H sums via MFMA ---------------------------------------------------
__global__ __launch_bounds__(256) void k_hgemm(
    const ushort_t* __restrict__ u_bf,
    const float* __restrict__ p_ar, const float* __restrict__ p_ai,
    const float* __restrict__ p_dr, const float* __restrict__ p_di,
    float2* __restrict__ Hbuf) {
  __shared__ ushort_t VLD[128][128];
  int d = blockIdx.x;
  int tid = threadIdx.x;
  int wv = tid >> 6, lane = tid & 63;
  int wm = wv >> 1, wn = wv & 1;
  int lrow = lane & 15, quad = lane >> 4;

  int m = tid & 127, chalf = tid >> 7;
  int nn = m >> 1, pp = m & 1;
  float ar = p_ar[d * 64 + nn], ai = p_ai[d * 64 + nn];
  float dr = p_dr[d * 64 + nn], di = p_di[d * 64 + nn];

  f32x4 acc[4][4];
#pragma unroll
  for (int mt = 0; mt < 4; ++mt)
#pragma unroll
    for (int nt = 0; nt < 4; ++nt) acc[mt][nt] = (f32x4){0.f, 0.f, 0.f, 0.f};

  for (int kt = 0; kt < 4; ++kt) {
    f2 z = cexp(dr, di, (float)(kt * 128 + chalf * 64));
#pragma unroll
    for (int g8 = 0; g8 < 8; ++g8) {
      ushort_t vals[8];
#pragma unroll
      for (int e = 0; e < 8; ++e) {
        vals[e] = f2bf(pp ? z.y : z.x);
        float zr = z.x * ar - z.y * ai;
        z.y = z.x * ai + z.y * ar;
        z.x = zr;
      }
      int g = (chalf * 64 + g8 * 8) >> 3;
      int gph = g ^ (m & 7);
      uint4 pk;
      pk.x = (uint_t)vals[0] | ((uint_t)vals[1] << 16);
      pk.y = (uint_t)vals[2] | ((uint_t)vals[3] << 16);
      pk.z = (uint_t)vals[4] | ((uint_t)vals[5] << 16);
      pk.w = (uint_t)vals[6] | ((uint_t)vals[7] << 16);
      *(uint4*)&VLD[m][gph << 3] = pk;
    }
    __syncthreads();
#pragma unroll
    for (int kb = 0; kb < 4; ++kb) {
      int kbase = kb * 32 + quad * 8;
      short8 af[4], bf[4];
#pragma unroll
      for (int mt = 0; mt < 4; ++mt) {
        int mrow = wm * 64 + mt * 16 + lrow;
        int gph = (kbase >> 3) ^ (mrow & 7);
        af[mt] = *(const short8*)&VLD[mrow][gph << 3];
      }
#pragma unroll
      for (int nt = 0; nt < 4; ++nt) {
        int col = wn * 64 + nt * 16 + lrow;
        int b = col >> 3, c = col & 7;
        bf[nt] = *(const short8*)(u_bf + (size_t)(b * 512 + d) * 4096 + c * 512 + kt * 128 + kbase);
      }
#pragma unroll
      for (int mt = 0; mt < 4; ++mt)
#pragma unroll
        for (int nt = 0; nt < 4; ++nt)
          acc[mt][nt] = __builtin_amdgcn_mfma_f32_16x16x32_bf16(af[mt], bf[nt], acc[mt][nt], 0, 0, 0);
    }
    __syncthreads();
  }
#pragma unroll
  for (int mt = 0; mt < 4; ++mt) {
#pragma unroll
    for (int nt = 0; nt < 4; ++nt) {
      int col = wn * 64 + nt * 16 + lrow;
      int b = col >> 3, c = col & 7;
      int m0 = wm * 64 + mt * 16 + quad * 4;
      int n0 = m0 >> 1;
      float4 v = {acc[mt][nt][0], acc[mt][nt][1], acc[mt][nt][2], acc[mt][nt][3]};
      *(float4*)((float*)(Hbuf + ((size_t)((b * 8 + c) * 512 + d)) * 64 + n0)) = v;
    }
  }
}

// ---- K2: kernel tail Kbuf[d][x] = K[3584+x]; x=511 carries +D[d] (diag = D*u)
// Throughput-form: 4 waves/block (one 128-x range each, seeded by cexp so there
// is no cross-wave recurrence), 16 x-values batched per reduce round so the
// 6-stage butterflies pipeline instead of serializing.
__global__ __launch_bounds__(256) void k_kc(
    const float* __restrict__ p_ar, const float* __restrict__ p_ai,
    const float* __restrict__ p_wr, const float* __restrict__ p_wi,
    const float* __restrict__ p_dr, const float* __restrict__ p_di,
    const float* __restrict__ Dvec, ushort_t* __restrict__ Kbuf) {
  int d = blockIdx.x;
  int tid = threadIdx.x;
  int lane = tid & 63;          // state n
  int x0 = (tid >> 6) * 128;    // wave's x-range base
  int i = d * 64 + lane;
  float ar = p_ar[i], ai = p_ai[i];
  float wr = p_wr[i], wi = p_wi[i];
  float Dd = Dvec[d];
  f2 e = cexp(p_dr[i], p_di[i], (float)(3584 + x0));
  float zr = wr * e.x - wi * e.y;
  float zi = wr * e.y + wi * e.x;
  for (int bb = 0; bb < 8; ++bb) {
    float s[16];
#pragma unroll
    for (int j = 0; j < 16; ++j) {
      s[j] = zr;
      float tr = zr * ar - zi * ai;
      zi = zr * ai + zi * ar;
      zr = tr;
    }
    float out = 0.f;
#pragma unroll
    for (int j = 0; j < 16; ++j) {
      float r = s[j];
#pragma unroll
      for (int off = 1; off < 64; off <<= 1) r += __shfl_xor(r, off, 64);
      if (lane == j) out = r;   // cndmask select: value j lands in lane j
    }
    if (lane < 16) {
      int x = x0 + bb * 16 + lane;
      Kbuf[d * 512 + x] = f2bf(x == 511 ? out + Dd : out);
    }
  }
}

// ---- K3: seeds. s[c] = A^((7-c)S) * F[cS-1], F excl own chunk. --------------
__global__ __launch_bounds__(256) void k_seedpack(
    const float* __restrict__ p_dr, const float* __restrict__ p_di,
    const float2* __restrict__ Hbuf, ushort_t* __restrict__ seedB) {
  __shared__ ushort_t tile[128 * 128];
  int d = blockIdx.x;
  int tid = threadIdx.x;
  int n = tid >> 2;      // 0..63
  int bq = tid & 3;
  float dr = p_dr[d * 64 + n], di = p_di[d * 64 + n];
  f2 AS = cexp(dr, di, 512.0f);
  f2 R[8];
  R[0] = (f2){1.f, 0.f};
#pragma unroll
  for (int c = 1; c < 8; ++c)
    R[c] = (f2){R[c-1].x * AS.x - R[c-1].y * AS.y, R[c-1].x * AS.y + R[c-1].y * AS.x};
  for (int bb = 0; bb < 4; ++bb) {
    int b = bq * 4 + bb;
    f2 G = {0.f, 0.f};
#pragma unroll
    for (int c = 0; c < 8; ++c) {
      f2 T = R[7 - c];
      float sr = T.x * G.x - T.y * G.y;
      float si = T.x * G.y + T.y * G.x;
      int col = b * 8 + c;
      tile[col * 128 + 2 * n]     = f2bf(sr);
      tile[col * 128 + 2 * n + 1] = f2bf(si);
      float2 h = Hbuf[((size_t)((b * 8 + c) * 512 + d)) * 64 + n];
      G.x += R[c].x * h.x - R[c].y * h.y;
      G.y += R[c].x * h.y + R[c].y * h.x;
    }
  }
  __syncthreads();
  const uint4* src = (const uint4*)tile;
  uint4* dst = (uint4*)(seedB + (size_t)d * 16384);
  for (int k = tid; k < 2048; k += 256) dst[k] = src[k];
}

// ---- K4: per-d Toeplitz + seed GEMM (MFMA), writes yraw (d,b,l) bf16 --------
// 1D grid 2048: id -> d = ((id>>5)<<3)|(id&7), t0 = ((id>>3)&3)*128.
// (4 tq-blocks of a d are 8 apart and id%8==d%8 -> same XCD -> u-slice L2 reuse)
#define KRN 1048
__global__ __launch_bounds__(256) void k_conv(
    const ushort_t* __restrict__ u_bf, const ushort_t* __restrict__ Kbuf,
    const ushort_t* __restrict__ seedB,
    const float* __restrict__ p_ar, const float* __restrict__ p_ai,
    const float* __restrict__ p_wr, const float* __restrict__ p_wi,
    const float* __restrict__ p_dr, const float* __restrict__ p_di,
    ushort_t* __restrict__ yraw) {
  __shared__ ushort_t KRc[8][KRN];
  __shared__ ushort_t PLD[128][136];
  int id = blockIdx.x;
  int d = ((id >> 5) << 3) | (id & 7);
  int t0 = ((id >> 3) & 3) * 128;
  int tid = threadIdx.x;

  for (int e = tid; e < 8 * KRN; e += 256) {
    int r = e / KRN, x = e - r * KRN;
    int y = x + r;
    KRc[r][x] = (y < 512) ? Kbuf[d * 512 + y] : (ushort_t)0;
  }
  {
    int n = tid & 63, mh = tid >> 6;
    int i = d * 64 + n;
    float ar = p_ar[i], ai = p_ai[i];
    float wr = p_wr[i], wi = p_wi[i];
    int mtop = mh * 32 + 31;
    f2 E = cexp(p_dr[i], p_di[i], (float)(511 - t0 - mtop));
    float zr = wr * E.x - wi * E.y;
    float zi = wr * E.y + wi * E.x;
    for (int m = mtop; m >= mh * 32; --m) {
      PLD[m][2 * n]     = f2bf(zr);
      PLD[m][2 * n + 1] = f2bf(-zi);
      float tr = zr * ar - zi * ai;
      zi = zr * ai + zi * ar;
      zr = tr;
    }
  }
  __syncthreads();

  int wv = tid >> 6, lane = tid & 63;
  int wm = wv >> 1, wn = wv & 1;
  int lrow = lane & 15, quad = lane >> 4;
  f32x4 acc[4][4];
#pragma unroll
  for (int mt = 0; mt < 4; ++mt)
#pragma unroll
    for (int nt = 0; nt < 4; ++nt) acc[mt][nt] = (f32x4){0.f, 0.f, 0.f, 0.f};

  for (int kt = 0; kt < 16; ++kt) {
    int kbase = kt * 32 + quad * 8;
    short8 af[4], bf[4];
#pragma unroll
    for (int mt = 0; mt < 4; ++mt) {
      int mr = wm * 64 + mt * 16 + lrow;
      int idx = 511 - t0 - mr + kbase;
      int r = idx & 7, st = idx - r;
      af[mt] = *(const short8*)&KRc[r][st];
    }
#pragma unroll
    for (int nt = 0; nt < 4; ++nt) {
      int col = wn * 64 + nt * 16 + lrow;
      int b = col >> 3, c = col & 7;
      bf[nt] = *(const short8*)(u_bf + (size_t)(b * 512 + d) * 4096 + c * 512 + kbase);
    }
#pragma unroll
    for (int mt = 0; mt < 4; ++mt)
#pragma unroll
      for (int nt = 0; nt < 4; ++nt)
        acc[mt][nt] = __builtin_amdgcn_mfma_f32_16x16x32_bf16(af[mt], bf[nt], acc[mt][nt], 0, 0, 0);
  }
  for (int kt = 0; kt < 4; ++kt) {
    int k2 = kt * 32 + quad * 8;
    short8 af[4], bf[4];
#pragma unroll
    for (int mt = 0; mt < 4; ++mt)
      af[mt] = *(const short8*)&PLD[wm * 64 + mt * 16 + lrow][k2];
#pragma unroll
    for (int nt = 0; nt < 4; ++nt) {
      int col = wn * 64 + nt * 16 + lrow;
      bf[nt] = *(const short8*)(seedB + (size_t)d * 16384 + col * 128 + k2);
    }
#pragma unroll
    for (int mt = 0; mt < 4; ++mt)
#pragma unroll
      for (int nt = 0; nt < 4; ++nt)
        acc[mt][nt] = __builtin_amdgcn_mfma_f32_16x16x32_bf16(af[mt], bf[nt], acc[mt][nt], 0, 0, 0);
  }

#pragma unroll
  for (int mt = 0; mt < 4; ++mt) {
#pragma unroll
    for (int nt = 0; nt < 4; ++nt) {
      int col = wn * 64 + nt * 16 + lrow;
      int b = col >> 3, c = col & 7;
      int tau = t0 + wm * 64 + mt * 16 + quad * 4;
      uint_t lo = (uint_t)f2bf(acc[mt][nt][0]) | ((uint_t)f2bf(acc[mt][nt][1]) << 16);
      uint_t hi = (uint_t)f2bf(acc[mt][nt][2]) | ((uint_t)f2bf(acc[mt][nt][3]) << 16);
      uint2 vv = {lo, hi};
      *(uint2*)(yraw + (size_t)d * 65536 + b * 4096 + c * 512 + tau) = vv;
    }
  }
}

// ---- K5: exact gelu + transpose: yraw (d,b,l) -> yg (b,l,d) bf16 ------------
// (D*u already folded into conv diagonal)
__global__ __launch_bounds__(256) void k_tg(
    const ushort_t* __restrict__ yraw, ushort_t* __restrict__ yg) {
  __shared__ ushort_t tile[64][72];
  int blk = blockIdx.x;
  int b = blk >> 9, dg = (blk >> 6) & 7, lg = blk & 63;
  int d0 = dg * 64, l0 = lg * 64;
  int tid = threadIdx.x;
  int dd = tid >> 2, lc = (tid & 3) * 16;

  const ushort_t* yp = yraw + (size_t)(d0 + dd) * 65536 + b * 4096 + l0 + lc;
  uint4 A0 = *(const uint4*)yp;
  uint4 A1 = *(const uint4*)(yp + 8);
  uint_t w[8] = {A0.x, A0.y, A0.z, A0.w, A1.x, A1.y, A1.z, A1.w};
#pragma unroll
  for (int i2 = 0; i2 < 16; ++i2) {
    ushort_t bits = (i2 & 1) ? (ushort_t)(w[i2 >> 1] >> 16) : (ushort_t)(w[i2 >> 1] & 0xffff);
    float y = bf2f(bits);
    float g = 0.5f * y * (1.0f + erff(y * 0.70710678118654752f));
    int row = lc + i2;
    int col = (dd + ((row >> 3) & 7) * 8) & 63;
    tile[row][col] = f2bf(g);
  }
  __syncthreads();
  int lr = tid >> 2, dc = (tid & 3) * 16;
  int rot = ((lr >> 3) & 7) * 8;
  int o1 = (dc + rot) & 63;
  int o2 = (dc + 8 + rot) & 63;
  uint4 v1 = *(const uint4*)&tile[lr][o1];
  uint4 v2 = *(const uint4*)&tile[lr][o2];
  ushort_t* og = yg + (size_t)b * (4096 * 512) + (size_t)(l0 + lr) * 512 + d0 + dc;
  *(uint4*)og = v1;
  *(uint4*)(og + 8) = v2;
}

// ---- 1x1 conv (512->1024) + bias + GLU + sum-over-L, fused ------------------
// 1D grid 4096: id -> p=id>>8, m=(id>>5)&7, q=id&31; n0=(p*32+q)*128, mp0=m*64.
// id%8==q%8 -> all 8 m-blocks of an n-tile on one XCD (yg L2 reuse).
// T3-minimum 2-phase schedule (learn_hip m230-V0 form): LDS double-buffer;
// STAGE(buf^1, kc+1) via global_load_lds issues BEFORE compute of buf[cur];
// the single __syncthreads() (drains vmcnt) sits AFTER compute, so the 8 DMA
// loads fly under the ~800-cyc compute phase instead of being drained cold.
// One barrier per tile (was two). Global source pre-swizzled (rule #21),
// LDS dest linear; read side swizzled, conflict-free.
__global__ __launch_bounds__(256) void k_gemm(
    const ushort_t* __restrict__ wbf, const ushort_t* __restrict__ yg,
    const float* __restrict__ b_out, float* __restrict__ pooled) {
  __shared__ ushort_t lwa[2][64][64];
  __shared__ ushort_t lwg[2][64][64];
  __shared__ ushort_t ly[2][128][64];
  int tid = threadIdx.x;
  int id = blockIdx.x;
  int p = id >> 8, m = (id >> 5) & 7, q = id & 31;
  int mp0 = m * 64;
  int n0 = (p * 32 + q) * 128;
  int b = n0 >> 12;
  int wv = tid >> 6, lane = tid & 63;
  int mh = wv >> 1, nh = wv & 1;
  int lrow = lane & 15, quad = lane >> 4;
  f32x4 accA[2][4], accG[2][4];
#pragma unroll
  for (int mt = 0; mt < 2; ++mt)
#pragma unroll
    for (int nt = 0; nt < 4; ++nt) {
      accA[mt][nt] = (f32x4){0.f, 0.f, 0.f, 0.f};
      accG[mt][nt] = (f32x4){0.f, 0.f, 0.f, 0.f};
    }

  // staging geometry: each gload16 covers 8 rows (1KB). lane c -> row sub=c>>3,
  // lds granule c&7; source granule (c&7)^(sub&7) [8-row groups keep row&7==sub&7]
  int sub = lane >> 3;
  int gsw = ((lane & 7) ^ (sub & 7)) * 8;   // pre-swizzled source col (ushorts)
  const ushort_t* gA0 = wbf + (size_t)(mp0 + wv * 16 + sub) * 512 + gsw;
  const ushort_t* gA1 = gA0 + 8 * 512;
  const ushort_t* gG0 = gA0 + (size_t)512 * 512;
  const ushort_t* gG1 = gA1 + (size_t)512 * 512;
  const ushort_t* gY0 = yg + (size_t)(n0 + wv * 32 + sub) * 512 + gsw;
  const ushort_t* gY1 = gY0 + 8 * 512;
  const ushort_t* gY2 = gY0 + 16 * 512;
  const ushort_t* gY3 = gY0 + 24 * 512;

  auto stage = [&](int kc, int bs) {
    int off = kc * 64;
    gload16(gA0 + off, &lwa[bs][wv * 16][0]);
    gload16(gA1 + off, &lwa[bs][wv * 16 + 8][0]);
    gload16(gG0 + off, &lwg[bs][wv * 16][0]);
    gload16(gG1 + off, &lwg[bs][wv * 16 + 8][0]);
    gload16(gY0 + off, &ly[bs][wv * 32][0]);
    gload16(gY1 + off, &ly[bs][wv * 32 + 8][0]);
    gload16(gY2 + off, &ly[bs][wv * 32 + 16][0]);
    gload16(gY3 + off, &ly[bs][wv * 32 + 24][0]);
  };

  stage(0, 0);
  __syncthreads();             // buf0 ready
  for (int kc = 0; kc < 8; ++kc) {
    int cur = kc & 1;
    if (kc < 7) stage(kc + 1, cur ^ 1);   // DMA flies under this tile's compute
#pragma unroll
    for (int kb = 0; kb < 2; ++kb) {
      int kg = kb * 4 + quad;   // granule index of ko
      short8 bfv[4], af[2], gf[2];
#pragma unroll
      for (int nt = 0; nt < 4; ++nt) {
        int row = nh * 64 + nt * 16 + lrow;
        bfv[nt] = *(const short8*)&ly[cur][row][(kg ^ (row & 7)) << 3];
      }
#pragma unroll
      for (int mt = 0; mt < 2; ++mt) {
        int row = mh * 32 + mt * 16 + lrow;
        af[mt] = *(const short8*)&lwa[cur][row][(kg ^ (row & 7)) << 3];
        gf[mt] = *(const short8*)&lwg[cur][row][(kg ^ (row & 7)) << 3];
      }
#pragma unroll
      for (int mt = 0; mt < 2; ++mt)
#pragma unroll
        for (int nt = 0; nt < 4; ++nt) {
          accA[mt][nt] = __builtin_amdgcn_mfma_f32_16x16x32_bf16(af[mt], bfv[nt], accA[mt][nt], 0, 0, 0);
          accG[mt][nt] = __builtin_amdgcn_mfma_f32_16x16x32_bf16(gf[mt], bfv[nt], accG[mt][nt], 0, 0, 0);
        }
    }
    __syncthreads();   // next buf's DMA done (vmcnt0) + this buf's reads done
  }
#pragma unroll
  for (int mt = 0; mt < 2; ++mt) {
#pragma unroll
    for (int reg = 0; reg < 4; ++reg) {
      int olocal = mh * 32 + mt * 16 + quad * 4 + reg;
      float ba = b_out[mp0 + olocal];
      float bg = b_out[512 + mp0 + olocal];
      float h = 0.f;
#pragma unroll
      for (int nt = 0; nt < 4; ++nt) {
        float a = accA[mt][nt][reg] + ba;
        float gv = accG[mt][nt][reg] + bg;
        h += a / (1.0f + __expf(-gv));
      }
#pragma unroll
      for (int off = 1; off < 16; off <<= 1) h += __shfl_xor(h, off, 16);
      if (lrow == 0) atomicAdd(&pooled[b * 512 + mp0 + olocal], h);
    }
  }
}

// ---- decoder ----------------------------------------------------------------
__global__ void k_final(const float* __restrict__ pooled, const float* __restrict__ W_dec,
                        const float* __restrict__ b_dec, float* __restrict__ out) {
  int b = blockIdx.x;
  int lane = threadIdx.x;
  float s = 0.f;
#pragma unroll
  for (int j = 0; j < 8; ++j) s += pooled[b * 512 + lane + 64 * j] * W_dec[lane + 64 * j];
#pragma unroll
  for (int off = 1; off < 64; off <<= 1) s += __shfl_xor(s, off, 64);
  if (lane == 0) out[b] = s * (1.0f / 4096.0f) + b_dec[0];
}

extern "C" void kernel_launch(void* const* d_in, const int* in_sizes, int n_in,
                              void* d_out, int out_size, void* d_ws, size_t ws_size,
                              hipStream_t stream) {
  const float* u          = (const float*)d_in[0];
  const float* log_dt     = (const float*)d_in[1];
  const float* log_A_real = (const float*)d_in[2];
  const float* A_imag     = (const float*)d_in[3];
  const float* B_re       = (const float*)d_in[4];
  const float* B_im       = (const float*)d_in[5];
  const float* C_re       = (const float*)d_in[6];
  const float* C_im       = (const float*)d_in[7];
  const float* Dv         = (const float*)d_in[8];
  const float* W_out      = (const float*)d_in[9];
  const float* b_out      = (const float*)d_in[10];
  const float* W_dec      = (const float*)d_in[11];
  const float* b_dec      = (const float*)d_in[12];

  float* ws = (float*)d_ws;
  float* p_ar = ws;
  float* p_ai = ws + 32768;
  float* p_wr = ws + 65536;
  float* p_wi = ws + 98304;
  float* p_dr = ws + 131072;
  float* p_di = ws + 163840;
  float* p_lr = ws + 196608;
  float* p_li = ws + 229376;
  float* pooled = (float*)((char*)d_ws + UOFF_POOLED);
  ushort_t* wbf   = (ushort_t*)((char*)d_ws + UOFF_WBF);
  ushort_t* u_bf  = (ushort_t*)((char*)d_ws + UOFF_UBF);
  ushort_t* yg    = (ushort_t*)((char*)d_ws + UOFF_UBF);    // alias: reused after k_conv
  ushort_t* yraw  = (ushort_t*)((char*)d_ws + UOFF_YRAW);
  float2*   Hbuf  = (float2*)((char*)d_ws + UOFF_YRAW);     // alias: dead before k_conv writes
  ushort_t* seedB = (ushort_t*)((char*)d_ws + UOFF_SEEDB);
  ushort_t* Kbuf  = (ushort_t*)((char*)d_ws + UOFF_KBUF);

  hipMemsetAsync(pooled, 0, 16 * 512 * sizeof(float), stream);
  k_params<<<128, 256, 0, stream>>>(log_dt, log_A_real, A_imag, B_re, B_im, C_re, C_im,
                                    p_ar, p_ai, p_wr, p_wi, p_dr, p_di, p_lr, p_li);
  k_wcvt<<<2048, 256, 0, stream>>>(W_out, wbf, 1024 * 512);
  k_ucvt<<<16384, 256, 0, stream>>>(u, u_bf);
  k_hgemm<<<512, 256, 0, stream>>>(u_bf, p_ar, p_ai, p_dr, p_di, Hbuf);
  k_kc<<<512, 256, 0, stream>>>(p_ar, p_ai, p_wr, p_wi, p_dr, p_di, Dv, Kbuf);
  k_seedpack<<<512, 256, 0, stream>>>(p_dr, p_di, Hbuf, seedB);
  k_conv<<<2048, 256, 0, stream>>>(u_bf, Kbuf, seedB,
                                   p_ar, p_ai, p_wr, p_wi, p_dr, p_di, yraw);
  k_tg<<<8192, 256, 0, stream>>>(yraw, yg);
  k_gemm<<<4096, 256, 0, stream>>>(wbf, yg, b_out, pooled);
  k_final<<<16, 64, 0, stream>>>(pooled, W_dec, b_dec, (float*)d_out);
}

// Round 7
// 503.211 us; speedup vs baseline: 1.0410x; 1.0410x over previous
//
#include <hip/hip_runtime.h>

// MiniS4D: B=16, D=512, N=64 states, L=4096, C=8 chunks of S=512.
// Pipeline: k_params -> k_wcvt -> k_ucvt (u->bf16) -> k_hgemm (Vandermonde MFMA -> H)
//           -> k_kc (kernel tail, D on diagonal) -> k_seedpack -> k_conv (Toeplitz+seed MFMA)
//           -> k_tg (gelu + transpose -> yg (b,l,d)) -> k_gemm (GLU) -> k_final
// ws byte layout (153.6 MB):
//   [0)          params: p_ar,p_ai,p_wr,p_wi,p_dr,p_di,p_lr,p_li (8 x 131072)
//   [1048576)    pooled 32KB
//   [1081344)    wbf 1MB
//   [2129920)    UBF  u_bf bf16 67.1MB   (ALIAS: yg reuses this region after k_conv)
//   [69238784)   YRAW bf16 67.1MB        (ALIAS: Hbuf float2 33.55MB in first half)
//   [136347648)  seedB bf16 16.8MB
//   [153124864)  Kbuf bf16 0.52MB  -> end 153649152

#define UOFF_POOLED 1048576
#define UOFF_WBF    1081344
#define UOFF_UBF    2129920
#define UOFF_YRAW   69238784
#define UOFF_SEEDB  136347648
#define UOFF_KBUF   153124864

typedef __attribute__((ext_vector_type(8))) short short8;
typedef __attribute__((ext_vector_type(4))) float f32x4;
typedef __attribute__((ext_vector_type(2))) float f2;
typedef unsigned short ushort_t;
typedef unsigned int uint_t;

__device__ __forceinline__ ushort_t f2bf(float f) {
  uint_t u = __float_as_uint(f);
  u = (u + 0x7FFF + ((u >> 16) & 1)) >> 16;  // RNE
  return (ushort_t)u;
}
__device__ __forceinline__ float bf2f(ushort_t v) {
  return __uint_as_float(((uint_t)v) << 16);
}

// async global->LDS 16B: linear LDS dest (wave-uniform base + lane*16)
__device__ __forceinline__ void gload16(const ushort_t* g, ushort_t* l) {
  __builtin_amdgcn_global_load_lds(
      (const __attribute__((address_space(1))) void*)g,
      (__attribute__((address_space(3))) void*)l, 16, 0, 0);
}

// exp(dr*t) * cis(di*t)
__device__ __forceinline__ f2 cexp(float dr, float di, float t) {
  float e = expf(dr * t);
  float ph = di * t;
  return (f2){e * cosf(ph), e * sinf(ph)};
}

// ---- derived SSM params ----------------------------------------------------
__global__ void k_params(const float* __restrict__ log_dt,
                         const float* __restrict__ log_A_real,
                         const float* __restrict__ A_imag,
                         const float* __restrict__ B_re, const float* __restrict__ B_im,
                         const float* __restrict__ C_re, const float* __restrict__ C_im,
                         float* __restrict__ p_ar, float* __restrict__ p_ai,
                         float* __restrict__ p_wr, float* __restrict__ p_wi,
                         float* __restrict__ p_dr, float* __restrict__ p_di,
                         float* __restrict__ p_lr, float* __restrict__ p_li) {
  int i = blockIdx.x * blockDim.x + threadIdx.x;   // 0..32767, d = i>>6
  int d = i >> 6;
  float dt  = expf(log_dt[d]);
  float Are = -expf(log_A_real[i]);
  float Aim = A_imag[i];
  float dre = dt * Are, dim = dt * Aim;
  float em  = expf(dre);
  float abr = em * cosf(dim);
  float abi = em * sinf(dim);
  float nr = abr - 1.0f, ni = abi;
  float inv = 1.0f / (Are * Are + Aim * Aim);
  float br = (nr * Are + ni * Aim) * inv;
  float bi = (ni * Are - nr * Aim) * inv;
  float Br = B_re[i], Bi = B_im[i];
  float b2r = br * Br - bi * Bi;
  float b2i = br * Bi + bi * Br;
  float Cr = C_re[i], Ci = C_im[i];
  p_ar[i] = abr; p_ai[i] = abi;
  p_wr[i] = Cr * b2r - Ci * b2i;
  p_wi[i] = Cr * b2i + Ci * b2r;
  p_dr[i] = dre; p_di[i] = dim;
  float eL = expf(dre * 4096.0f);
  float phL = dim * 4096.0f;
  p_lr[i] = eL * cosf(phL);
  p_li[i] = eL * sinf(phL);
}

// ---- W_out fp32 -> bf16 -----------------------------------------------------
__global__ void k_wcvt(const float* __restrict__ w, ushort_t* __restrict__ wb, int n) {
  int i = blockIdx.x * blockDim.x + threadIdx.x;
  if (i < n) wb[i] = f2bf(w[i]);
}

// ---- u fp32 -> bf16 (8 elems/thread) ---------------------------------------
__global__ __launch_bounds__(256) void k_ucvt(const float* __restrict__ u,
                                              ushort_t* __restrict__ u_bf) {
  size_t i = (size_t)blockIdx.x * 256 + threadIdx.x;   // per 8 elems
  const float4* p = (const float4*)u + 2 * i;
  float4 a = p[0], b = p[1];
  uint4 v;
  v.x = (uint_t)f2bf(a.x) | ((uint_t)f2bf(a.y) << 16);
  v.y = (uint_t)f2bf(a.z) | ((uint_t)f2bf(a.w) << 16);
  v.z = (uint_t)f2bf(b.x) | ((uint_t)f2bf(b.y) << 16);
  v.w = (uint_t)f2bf(b.z) | ((uint_t)f2bf(b.w) << 16);
  ((uint4*)u_bf)[i] = v;
}

// ---- K1: H sums via MFMA ---------------------------------------------------
// VLD double-buffered: generation of tile kt+1 (pure VALU) overlaps the MFMA
// phase of tile kt across the block's 8 waves (separate pipes, m114). LDS
// 64KB is free here: occupancy is grid-bound at 2 blocks/CU (512 blocks).
// One barrier per kt (was two).
__global__ __launch_bounds__(256) void k_hgemm(
    const ushort_t* __restrict__ u_bf,
    const float* __restrict__ p_ar, const float* __restrict__ p_ai,
    const float* __restrict__ p_dr, const float* __restrict__ p_di,
    float2* __restrict__ Hbuf) {
  __shared__ ushort_t VLD[2][128][128];
  int d = blockIdx.x;
  int tid = threadIdx.x;
  int wv = tid >> 6, lane = tid & 63;
  int wm = wv >> 1, wn = wv & 1;
  int lrow = lane & 15, quad = lane >> 4;

  int m = tid & 127, chalf = tid >> 7;
  int nn = m >> 1, pp = m & 1;
  float ar = p_ar[d * 64 + nn], ai = p_ai[d * 64 + nn];
  float dr = p_dr[d * 64 + nn], di = p_di[d * 64 + nn];

  f32x4 acc[4][4];
#pragma unroll
  for (int mt = 0; mt < 4; ++mt)
#pragma unroll
    for (int nt = 0; nt < 4; ++nt) acc[mt][nt] = (f32x4){0.f, 0.f, 0.f, 0.f};

  auto gen = [&](int kt, int bs) {
    f2 z = cexp(dr, di, (float)(kt * 128 + chalf * 64));
#pragma unroll
    for (int g8 = 0; g8 < 8; ++g8) {
      ushort_t vals[8];
#pragma unroll
      for (int e = 0; e < 8; ++e) {
        vals[e] = f2bf(pp ? z.y : z.x);
        float zr = z.x * ar - z.y * ai;
        z.y = z.x * ai + z.y * ar;
        z.x = zr;
      }
      int g = (chalf * 64 + g8 * 8) >> 3;
      int gph = g ^ (m & 7);
      uint4 pk;
      pk.x = (uint_t)vals[0] | ((uint_t)vals[1] << 16);
      pk.y = (uint_t)vals[2] | ((uint_t)vals[3] << 16);
      pk.z = (uint_t)vals[4] | ((uint_t)vals[5] << 16);
      pk.w = (uint_t)vals[6] | ((uint_t)vals[7] << 16);
      *(uint4*)&VLD[bs][m][gph << 3] = pk;
    }
  };

  gen(0, 0);
  __syncthreads();
  for (int kt = 0; kt < 4; ++kt) {
    int cur = kt & 1;
    if (kt < 3) gen(kt + 1, cur ^ 1);   // VALU gen overlaps MFMA below
#pragma unroll
    for (int kb = 0; kb < 4; ++kb) {
      int kbase = kb * 32 + quad * 8;
      short8 af[4], bf[4];
#pragma unroll
      for (int mt = 0; mt < 4; ++mt) {
        int mrow = wm * 64 + mt * 16 + lrow;
        int gph = (kbase >> 3) ^ (mrow & 7);
        af[mt] = *(const short8*)&VLD[cur][mrow][gph << 3];
      }
#pragma unroll
      for (int nt = 0; nt < 4; ++nt) {
        int col = wn * 64 + nt * 16 + lrow;
        int b = col >> 3, c = col & 7;
        bf[nt] = *(const short8*)(u_bf + (size_t)(b * 512 + d) * 4096 + c * 512 + kt * 128 + kbase);
      }
#pragma unroll
      for (int mt = 0; mt < 4; ++mt)
#pragma unroll
        for (int nt = 0; nt < 4; ++nt)
          acc[mt][nt] = __builtin_amdgcn_mfma_f32_16x16x32_bf16(af[mt], bf[nt], acc[mt][nt], 0, 0, 0);
    }
    __syncthreads();   // gen(kt+1) complete + reads of cur done
  }
#pragma unroll
  for (int mt = 0; mt < 4; ++mt) {
#pragma unroll
    for (int nt = 0; nt < 4; ++nt) {
      int col = wn * 64 + nt * 16 + lrow;
      int b = col >> 3, c = col & 7;
      int m0 = wm * 64 + mt * 16 + quad * 4;
      int n0 = m0 >> 1;
      float4 v = {acc[mt][nt][0], acc[mt][nt][1], acc[mt][nt][2], acc[mt][nt][3]};
      *(float4*)((float*)(Hbuf + ((size_t)((b * 8 + c) * 512 + d)) * 64 + n0)) = v;
    }
  }
}

// ---- K2: kernel tail Kbuf[d][x] = K[3584+x]; x=511 carries +D[d] (diag = D*u)
// Throughput-form: 4 waves/block (one 128-x range each, seeded by cexp so there
// is no cross-wave recurrence), 16 x-values batched per reduce round so the
// 6-stage butterflies pipeline instead of serializing.
__global__ __launch_bounds__(256) void k_kc(
    const float* __restrict__ p_ar, const float* __restrict__ p_ai,
    const float* __restrict__ p_wr, const float* __restrict__ p_wi,
    const float* __restrict__ p_dr, const float* __restrict__ p_di,
    const float* __restrict__ Dvec, ushort_t* __restrict__ Kbuf) {
  int d = blockIdx.x;
  int tid = threadIdx.x;
  int lane = tid & 63;          // state n
  int x0 = (tid >> 6) * 128;    // wave's x-range base
  int i = d * 64 + lane;
  float ar = p_ar[i], ai = p_ai[i];
  float wr = p_wr[i], wi = p_wi[i];
  float Dd = Dvec[d];
  f2 e = cexp(p_dr[i], p_di[i], (float)(3584 + x0));
  float zr = wr * e.x - wi * e.y;
  float zi = wr * e.y + wi * e.x;
  for (int bb = 0; bb < 8; ++bb) {
    float s[16];
#pragma unroll
    for (int j = 0; j < 16; ++j) {
      s[j] = zr;
      float tr = zr * ar - zi * ai;
      zi = zr * ai + zi * ar;
      zr = tr;
    }
    float out = 0.f;
#pragma unroll
    for (int j = 0; j < 16; ++j) {
      float r = s[j];
#pragma unroll
      for (int off = 1; off < 64; off <<= 1) r += __shfl_xor(r, off, 64);
      if (lane == j) out = r;   // cndmask select: value j lands in lane j
    }
    if (lane < 16) {
      int x = x0 + bb * 16 + lane;
      Kbuf[d * 512 + x] = f2bf(x == 511 ? out + Dd : out);
    }
  }
}

// ---- K3: seeds. s[c] = A^((7-c)S) * F[cS-1], F excl own chunk. --------------
__global__ __launch_bounds__(256) void k_seedpack(
    const float* __restrict__ p_dr, const float* __restrict__ p_di,
    const float2* __restrict__ Hbuf, ushort_t* __restrict__ seedB) {
  __shared__ ushort_t tile[128 * 128];
  int d = blockIdx.x;
  int tid = threadIdx.x;
  int n = tid >> 2;      // 0..63
  int bq = tid & 3;
  float dr = p_dr[d * 64 + n], di = p_di[d * 64 + n];
  f2 AS = cexp(dr, di, 512.0f);
  f2 R[8];
  R[0] = (f2){1.f, 0.f};
#pragma unroll
  for (int c = 1; c < 8; ++c)
    R[c] = (f2){R[c-1].x * AS.x - R[c-1].y * AS.y, R[c-1].x * AS.y + R[c-1].y * AS.x};
  for (int bb = 0; bb < 4; ++bb) {
    int b = bq * 4 + bb;
    f2 G = {0.f, 0.f};
#pragma unroll
    for (int c = 0; c < 8; ++c) {
      f2 T = R[7 - c];
      float sr = T.x * G.x - T.y * G.y;
      float si = T.x * G.y + T.y * G.x;
      int col = b * 8 + c;
      tile[col * 128 + 2 * n]     = f2bf(sr);
      tile[col * 128 + 2 * n + 1] = f2bf(si);
      float2 h = Hbuf[((size_t)((b * 8 + c) * 512 + d)) * 64 + n];
      G.x += R[c].x * h.x - R[c].y * h.y;
      G.y += R[c].x * h.y + R[c].y * h.x;
    }
  }
  __syncthreads();
  const uint4* src = (const uint4*)tile;
  uint4* dst = (uint4*)(seedB + (size_t)d * 16384);
  for (int k = tid; k < 2048; k += 256) dst[k] = src[k];
}

// ---- K4: per-d Toeplitz + seed GEMM (MFMA), writes yraw (d,b,l) bf16 --------
// 1D grid 2048: id -> d = ((id>>5)<<3)|(id&7), t0 = ((id>>3)&3)*128.
// (4 tq-blocks of a d are 8 apart and id%8==d%8 -> same XCD -> u-slice L2 reuse)
#define KRN 1048
__global__ __launch_bounds__(256) void k_conv(
    const ushort_t* __restrict__ u_bf, const ushort_t* __restrict__ Kbuf,
    const ushort_t* __restrict__ seedB,
    const float* __restrict__ p_ar, const float* __restrict__ p_ai,
    const float* __restrict__ p_wr, const float* __restrict__ p_wi,
    const float* __restrict__ p_dr, const float* __restrict__ p_di,
    ushort_t* __restrict__ yraw) {
  __shared__ ushort_t KRc[8][KRN];
  __shared__ ushort_t PLD[128][136];
  int id = blockIdx.x;
  int d = ((id >> 5) << 3) | (id & 7);
  int t0 = ((id >> 3) & 3) * 128;
  int tid = threadIdx.x;

  for (int e = tid; e < 8 * KRN; e += 256) {
    int r = e / KRN, x = e - r * KRN;
    int y = x + r;
    KRc[r][x] = (y < 512) ? Kbuf[d * 512 + y] : (ushort_t)0;
  }
  {
    int n = tid & 63, mh = tid >> 6;
    int i = d * 64 + n;
    float ar = p_ar[i], ai = p_ai[i];
    float wr = p_wr[i], wi = p_wi[i];
    int mtop = mh * 32 + 31;
    f2 E = cexp(p_dr[i], p_di[i], (float)(511 - t0 - mtop));
    float zr = wr * E.x - wi * E.y;
    float zi = wr * E.y + wi * E.x;
    for (int m = mtop; m >= mh * 32; --m) {
      PLD[m][2 * n]     = f2bf(zr);
      PLD[m][2 * n + 1] = f2bf(-zi);
      float tr = zr * ar - zi * ai;
      zi = zr * ai + zi * ar;
      zr = tr;
    }
  }
  __syncthreads();

  int wv = tid >> 6, lane = tid & 63;
  int wm = wv >> 1, wn = wv & 1;
  int lrow = lane & 15, quad = lane >> 4;
  f32x4 acc[4][4];
#pragma unroll
  for (int mt = 0; mt < 4; ++mt)
#pragma unroll
    for (int nt = 0; nt < 4; ++nt) acc[mt][nt] = (f32x4){0.f, 0.f, 0.f, 0.f};

  for (int kt = 0; kt < 16; ++kt) {
    int kbase = kt * 32 + quad * 8;
    short8 af[4], bf[4];
#pragma unroll
    for (int mt = 0; mt < 4; ++mt) {
      int mr = wm * 64 + mt * 16 + lrow;
      int idx = 511 - t0 - mr + kbase;
      int r = idx & 7, st = idx - r;
      af[mt] = *(const short8*)&KRc[r][st];
    }
#pragma unroll
    for (int nt = 0; nt < 4; ++nt) {
      int col = wn * 64 + nt * 16 + lrow;
      int b = col >> 3, c = col & 7;
      bf[nt] = *(const short8*)(u_bf + (size_t)(b * 512 + d) * 4096 + c * 512 + kbase);
    }
#pragma unroll
    for (int mt = 0; mt < 4; ++mt)
#pragma unroll
      for (int nt = 0; nt < 4; ++nt)
        acc[mt][nt] = __builtin_amdgcn_mfma_f32_16x16x32_bf16(af[mt], bf[nt], acc[mt][nt], 0, 0, 0);
  }
  for (int kt = 0; kt < 4; ++kt) {
    int k2 = kt * 32 + quad * 8;
    short8 af[4], bf[4];
#pragma unroll
    for (int mt = 0; mt < 4; ++mt)
      af[mt] = *(const short8*)&PLD[wm * 64 + mt * 16 + lrow][k2];
#pragma unroll
    for (int nt = 0; nt < 4; ++nt) {
      int col = wn * 64 + nt * 16 + lrow;
      bf[nt] = *(const short8*)(seedB + (size_t)d * 16384 + col * 128 + k2);
    }
#pragma unroll
    for (int mt = 0; mt < 4; ++mt)
#pragma unroll
      for (int nt = 0; nt < 4; ++nt)
        acc[mt][nt] = __builtin_amdgcn_mfma_f32_16x16x32_bf16(af[mt], bf[nt], acc[mt][nt], 0, 0, 0);
  }

#pragma unroll
  for (int mt = 0; mt < 4; ++mt) {
#pragma unroll
    for (int nt = 0; nt < 4; ++nt) {
      int col = wn * 64 + nt * 16 + lrow;
      int b = col >> 3, c = col & 7;
      int tau = t0 + wm * 64 + mt * 16 + quad * 4;
      uint_t lo = (uint_t)f2bf(acc[mt][nt][0]) | ((uint_t)f2bf(acc[mt][nt][1]) << 16);
      uint_t hi = (uint_t)f2bf(acc[mt][nt][2]) | ((uint_t)f2bf(acc[mt][nt][3]) << 16);
      uint2 vv = {lo, hi};
      *(uint2*)(yraw + (size_t)d * 65536 + b * 4096 + c * 512 + tau) = vv;
    }
  }
}

// ---- K5: exact gelu + transpose: yraw (d,b,l) -> yg (b,l,d) bf16 ------------
// (D*u already folded into conv diagonal)
__global__ __launch_bounds__(256) void k_tg(
    const ushort_t* __restrict__ yraw, ushort_t* __restrict__ yg) {
  __shared__ ushort_t tile[64][72];
  int blk = blockIdx.x;
  int b = blk >> 9, dg = (blk >> 6) & 7, lg = blk & 63;
  int d0 = dg * 64, l0 = lg * 64;
  int tid = threadIdx.x;
  int dd = tid >> 2, lc = (tid & 3) * 16;

  const ushort_t* yp = yraw + (size_t)(d0 + dd) * 65536 + b * 4096 + l0 + lc;
  uint4 A0 = *(const uint4*)yp;
  uint4 A1 = *(const uint4*)(yp + 8);
  uint_t w[8] = {A0.x, A0.y, A0.z, A0.w, A1.x, A1.y, A1.z, A1.w};
#pragma unroll
  for (int i2 = 0; i2 < 16; ++i2) {
    ushort_t bits = (i2 & 1) ? (ushort_t)(w[i2 >> 1] >> 16) : (ushort_t)(w[i2 >> 1] & 0xffff);
    float y = bf2f(bits);
    float g = 0.5f * y * (1.0f + erff(y * 0.70710678118654752f));
    int row = lc + i2;
    int col = (dd + ((row >> 3) & 7) * 8) & 63;
    tile[row][col] = f2bf(g);
  }
  __syncthreads();
  int lr = tid >> 2, dc = (tid & 3) * 16;
  int rot = ((lr >> 3) & 7) * 8;
  int o1 = (dc + rot) & 63;
  int o2 = (dc + 8 + rot) & 63;
  uint4 v1 = *(const uint4*)&tile[lr][o1];
  uint4 v2 = *(const uint4*)&tile[lr][o2];
  ushort_t* og = yg + (size_t)b * (4096 * 512) + (size_t)(l0 + lr) * 512 + d0 + dc;
  *(uint4*)og = v1;
  *(uint4*)(og + 8) = v2;
}

// ---- 1x1 conv (512->1024) + bias + GLU + sum-over-L, fused ------------------
// 1D grid 4096: id -> p=id>>8, m=(id>>5)&7, q=id&31; n0=(p*32+q)*128, mp0=m*64.
// id%8==q%8 -> all 8 m-blocks of an n-tile on one XCD (yg L2 reuse).
// R5 form (best measured: 106us): single-buffer + global_load_lds staging,
// linear LDS dest + pre-swizzled global source (rule #21), swizzled reads,
// conflict-free, 32KB LDS (~5 blocks/CU). Explicit dbuf REGRESSED (R6: 133us,
// occupancy 30->22%) - do not re-add (m99/m100 lesson).
__global__ __launch_bounds__(256) void k_gemm(
    const ushort_t* __restrict__ wbf, const ushort_t* __restrict__ yg,
    const float* __restrict__ b_out, float* __restrict__ pooled) {
  __shared__ ushort_t lwa[64][64];
  __shared__ ushort_t lwg[64][64];
  __shared__ ushort_t ly[128][64];
  int tid = threadIdx.x;
  int id = blockIdx.x;
  int p = id >> 8, m = (id >> 5) & 7, q = id & 31;
  int mp0 = m * 64;
  int n0 = (p * 32 + q) * 128;
  int b = n0 >> 12;
  int wv = tid >> 6, lane = tid & 63;
  int mh = wv >> 1, nh = wv & 1;
  int lrow = lane & 15, quad = lane >> 4;
  f32x4 accA[2][4], accG[2][4];
#pragma unroll
  for (int mt = 0; mt < 2; ++mt)
#pragma unroll
    for (int nt = 0; nt < 4; ++nt) {
      accA[mt][nt] = (f32x4){0.f, 0.f, 0.f, 0.f};
      accG[mt][nt] = (f32x4){0.f, 0.f, 0.f, 0.f};
    }

  // staging geometry: each gload16 covers 8 rows (1KB). lane c -> row sub=c>>3,
  // lds granule c&7; source granule (c&7)^(sub&7) [8-row groups keep row&7==sub&7]
  int sub = lane >> 3;
  int gsw = ((lane & 7) ^ (sub & 7)) * 8;   // pre-swizzled source col (ushorts)
  const ushort_t* gA0 = wbf + (size_t)(mp0 + wv * 16 + sub) * 512 + gsw;
  const ushort_t* gA1 = gA0 + 8 * 512;
  const ushort_t* gG0 = gA0 + (size_t)512 * 512;
  const ushort_t* gG1 = gA1 + (size_t)512 * 512;
  const ushort_t* gY0 = yg + (size_t)(n0 + wv * 32 + sub) * 512 + gsw;
  const ushort_t* gY1 = gY0 + 8 * 512;
  const ushort_t* gY2 = gY0 + 16 * 512;
  const ushort_t* gY3 = gY0 + 24 * 512;
  ushort_t* lA0 = &lwa[wv * 16][0];
  ushort_t* lA1 = &lwa[wv * 16 + 8][0];
  ushort_t* lG0 = &lwg[wv * 16][0];
  ushort_t* lG1 = &lwg[wv * 16 + 8][0];
  ushort_t* lY0 = &ly[wv * 32][0];
  ushort_t* lY1 = &ly[wv * 32 + 8][0];
  ushort_t* lY2 = &ly[wv * 32 + 16][0];
  ushort_t* lY3 = &ly[wv * 32 + 24][0];

  for (int kc = 0; kc < 8; ++kc) {
    int off = kc * 64;
    gload16(gA0 + off, lA0);
    gload16(gA1 + off, lA1);
    gload16(gG0 + off, lG0);
    gload16(gG1 + off, lG1);
    gload16(gY0 + off, lY0);
    gload16(gY1 + off, lY1);
    gload16(gY2 + off, lY2);
    gload16(gY3 + off, lY3);
    __syncthreads();
#pragma unroll
    for (int kb = 0; kb < 2; ++kb) {
      int kg = kb * 4 + quad;   // granule index of ko
      short8 bfv[4], af[2], gf[2];
#pragma unroll
      for (int nt = 0; nt < 4; ++nt) {
        int row = nh * 64 + nt * 16 + lrow;
        bfv[nt] = *(const short8*)&ly[row][(kg ^ (row & 7)) << 3];
      }
#pragma unroll
      for (int mt = 0; mt < 2; ++mt) {
        int row = mh * 32 + mt * 16 + lrow;
        af[mt] = *(const short8*)&lwa[row][(kg ^ (row & 7)) << 3];
        gf[mt] = *(const short8*)&lwg[row][(kg ^ (row & 7)) << 3];
      }
#pragma unroll
      for (int mt = 0; mt < 2; ++mt)
#pragma unroll
        for (int nt = 0; nt < 4; ++nt) {
          accA[mt][nt] = __builtin_amdgcn_mfma_f32_16x16x32_bf16(af[mt], bfv[nt], accA[mt][nt], 0, 0, 0);
          accG[mt][nt] = __builtin_amdgcn_mfma_f32_16x16x32_bf16(gf[mt], bfv[nt], accG[mt][nt], 0, 0, 0);
        }
    }
    __syncthreads();   // all reads done before next tile's DMA overwrites
  }
#pragma unroll
  for (int mt = 0; mt < 2; ++mt) {
#pragma unroll
    for (int reg = 0; reg < 4; ++reg) {
      int olocal = mh * 32 + mt * 16 + quad * 4 + reg;
      float ba = b_out[mp0 + olocal];
      float bg = b_out[512 + mp0 + olocal];
      float h = 0.f;
#pragma unroll
      for (int nt = 0; nt < 4; ++nt) {
        float a = accA[mt][nt][reg] + ba;
        float gv = accG[mt][nt][reg] + bg;
        h += a / (1.0f + __expf(-gv));
      }
#pragma unroll
      for (int off = 1; off < 16; off <<= 1) h += __shfl_xor(h, off, 16);
      if (lrow == 0) atomicAdd(&pooled[b * 512 + mp0 + olocal], h);
    }
  }
}

// ---- decoder ----------------------------------------------------------------
__global__ void k_final(const float* __restrict__ pooled, const float* __restrict__ W_dec,
                        const float* __restrict__ b_dec, float* __restrict__ out) {
  int b = blockIdx.x;
  int lane = threadIdx.x;
  float s = 0.f;
#pragma unroll
  for (int j = 0; j < 8; ++j) s += pooled[b * 512 + lane + 64 * j] * W_dec[lane + 64 * j];
#pragma unroll
  for (int off = 1; off < 64; off <<= 1) s += __shfl_xor(s, off, 64);
  if (lane == 0) out[b] = s * (1.0f / 4096.0f) + b_dec[0];
}

extern "C" void kernel_launch(void* const* d_in, const int* in_sizes, int n_in,
                              void* d_out, int out_size, void* d_ws, size_t ws_size,
                              hipStream_t stream) {
  const float* u          = (const float*)d_in[0];
  const float* log_dt     = (const float*)d_in[1];
  const float* log_A_real = (const float*)d_in[2];
  const float* A_imag     = (const float*)d_in[3];
  const float* B_re       = (const float*)d_in[4];
  const float* B_im       = (const float*)d_in[5];
  const float* C_re       = (const float*)d_in[6];
  const float* C_im       = (const float*)d_in[7];
  const float* Dv         = (const float*)d_in[8];
  const float* W_out      = (const float*)d_in[9];
  const float* b_out      = (const float*)d_in[10];
  const float* W_dec      = (const float*)d_in[11];
  const float* b_dec      = (const float*)d_in[12];

  float* ws = (float*)d_ws;
  float* p_ar = ws;
  float* p_ai = ws + 32768;
  float* p_wr = ws + 65536;
  float* p_wi = ws + 98304;
  float* p_dr = ws + 131072;
  float* p_di = ws + 163840;
  float* p_lr = ws + 196608;
  float* p_li = ws + 229376;
  float* pooled = (float*)((char*)d_ws + UOFF_POOLED);
  ushort_t* wbf   = (ushort_t*)((char*)d_ws + UOFF_WBF);
  ushort_t* u_bf  = (ushort_t*)((char*)d_ws + UOFF_UBF);
  ushort_t* yg    = (ushort_t*)((char*)d_ws + UOFF_UBF);    // alias: reused after k_conv
  ushort_t* yraw  = (ushort_t*)((char*)d_ws + UOFF_YRAW);
  float2*   Hbuf  = (float2*)((char*)d_ws + UOFF_YRAW);     // alias: dead before k_conv writes
  ushort_t* seedB = (ushort_t*)((char*)d_ws + UOFF_SEEDB);
  ushort_t* Kbuf  = (ushort_t*)((char*)d_ws + UOFF_KBUF);

  hipMemsetAsync(pooled, 0, 16 * 512 * sizeof(float), stream);
  k_params<<<128, 256, 0, stream>>>(log_dt, log_A_real, A_imag, B_re, B_im, C_re, C_im,
                                    p_ar, p_ai, p_wr, p_wi, p_dr, p_di, p_lr, p_li);
  k_wcvt<<<2048, 256, 0, stream>>>(W_out, wbf, 1024 * 512);
  k_ucvt<<<16384, 256, 0, stream>>>(u, u_bf);
  k_hgemm<<<512, 256, 0, stream>>>(u_bf, p_ar, p_ai, p_dr, p_di, Hbuf);
  k_kc<<<512, 256, 0, stream>>>(p_ar, p_ai, p_wr, p_wi, p_dr, p_di, Dv, Kbuf);
  k_seedpack<<<512, 256, 0, stream>>>(p_dr, p_di, Hbuf, seedB);
  k_conv<<<2048, 256, 0, stream>>>(u_bf, Kbuf, seedB,
                                   p_ar, p_ai, p_wr, p_wi, p_dr, p_di, yraw);
  k_tg<<<8192, 256, 0, stream>>>(yraw, yg);
  k_gemm<<<4096, 256, 0, stream>>>(wbf, yg, b_out, pooled);
  k_final<<<16, 64, 0, stream>>>(pooled, W_dec, b_dec, (float*)d_out);
}

// Round 8
// 497.041 us; speedup vs baseline: 1.0539x; 1.0124x over previous
//
#include <hip/hip_runtime.h>

// MiniS4D: B=16, D=512, N=64 states, L=4096, C=8 chunks of S=512.
// Pipeline (7 launches): k_prep (params+wcvt+ucvt fused) -> k_hk (hgemm + kc
// interleaved) -> k_seedpack -> k_conv -> k_tg -> k_gemm -> k_final
// ws byte layout (153.6 MB):
//   [0)          params: p_ar,p_ai,p_wr,p_wi,p_dr,p_di,p_lr,p_li (8 x 131072)
//   [1048576)    pooled 32KB
//   [1081344)    wbf 1MB
//   [2129920)    UBF  u_bf bf16 67.1MB   (ALIAS: yg reuses this region after k_conv)
//   [69238784)   YRAW bf16 67.1MB        (ALIAS: Hbuf float2 33.55MB in first half)
//   [136347648)  seedB bf16 16.8MB
//   [153124864)  Kbuf bf16 0.52MB  -> end 153649152

#define UOFF_POOLED 1048576
#define UOFF_WBF    1081344
#define UOFF_UBF    2129920
#define UOFF_YRAW   69238784
#define UOFF_SEEDB  136347648
#define UOFF_KBUF   153124864

typedef __attribute__((ext_vector_type(8))) short short8;
typedef __attribute__((ext_vector_type(4))) float f32x4;
typedef __attribute__((ext_vector_type(2))) float f2;
typedef unsigned short ushort_t;
typedef unsigned int uint_t;

__device__ __forceinline__ ushort_t f2bf(float f) {
  uint_t u = __float_as_uint(f);
  u = (u + 0x7FFF + ((u >> 16) & 1)) >> 16;  // RNE
  return (ushort_t)u;
}
__device__ __forceinline__ float bf2f(ushort_t v) {
  return __uint_as_float(((uint_t)v) << 16);
}

// async global->LDS 16B: linear LDS dest (wave-uniform base + lane*16)
__device__ __forceinline__ void gload16(const ushort_t* g, ushort_t* l) {
  __builtin_amdgcn_global_load_lds(
      (const __attribute__((address_space(1))) void*)g,
      (__attribute__((address_space(3))) void*)l, 16, 0, 0);
}

// exp(dr*t) * cis(di*t)
__device__ __forceinline__ f2 cexp(float dr, float di, float t) {
  float e = expf(dr * t);
  float ph = di * t;
  return (f2){e * cosf(ph), e * sinf(ph)};
}

// ---- fused prep: u->bf16 (16384 blk) | W_out->bf16 (2048 blk) | params (128)
__global__ __launch_bounds__(256) void k_prep(
    const float* __restrict__ u, ushort_t* __restrict__ u_bf,
    const float* __restrict__ W_out, ushort_t* __restrict__ wbf,
    const float* __restrict__ log_dt, const float* __restrict__ log_A_real,
    const float* __restrict__ A_imag,
    const float* __restrict__ B_re, const float* __restrict__ B_im,
    const float* __restrict__ C_re, const float* __restrict__ C_im,
    float* __restrict__ p_ar, float* __restrict__ p_ai,
    float* __restrict__ p_wr, float* __restrict__ p_wi,
    float* __restrict__ p_dr, float* __restrict__ p_di,
    float* __restrict__ p_lr, float* __restrict__ p_li) {
  int bid = blockIdx.x;
  if (bid < 16384) {                       // ---- u fp32 -> bf16, 8 elems/thread
    size_t i = (size_t)bid * 256 + threadIdx.x;
    const float4* p = (const float4*)u + 2 * i;
    float4 a = p[0], b = p[1];
    uint4 v;
    v.x = (uint_t)f2bf(a.x) | ((uint_t)f2bf(a.y) << 16);
    v.y = (uint_t)f2bf(a.z) | ((uint_t)f2bf(a.w) << 16);
    v.z = (uint_t)f2bf(b.x) | ((uint_t)f2bf(b.y) << 16);
    v.w = (uint_t)f2bf(b.z) | ((uint_t)f2bf(b.w) << 16);
    ((uint4*)u_bf)[i] = v;
  } else if (bid < 16384 + 2048) {         // ---- W_out fp32 -> bf16
    int i = (bid - 16384) * 256 + threadIdx.x;
    if (i < 1024 * 512) wbf[i] = f2bf(W_out[i]);
  } else {                                 // ---- derived SSM params
    int i = (bid - 18432) * 256 + threadIdx.x;   // 0..32767
    int d = i >> 6;
    float dt  = expf(log_dt[d]);
    float Are = -expf(log_A_real[i]);
    float Aim = A_imag[i];
    float dre = dt * Are, dim = dt * Aim;
    float em  = expf(dre);
    float abr = em * cosf(dim);
    float abi = em * sinf(dim);
    float nr = abr - 1.0f, ni = abi;
    float inv = 1.0f / (Are * Are + Aim * Aim);
    float br = (nr * Are + ni * Aim) * inv;
    float bi = (ni * Are - nr * Aim) * inv;
    float Br = B_re[i], Bi = B_im[i];
    float b2r = br * Br - bi * Bi;
    float b2i = br * Bi + bi * Br;
    float Cr = C_re[i], Ci = C_im[i];
    p_ar[i] = abr; p_ai[i] = abi;
    p_wr[i] = Cr * b2r - Ci * b2i;
    p_wi[i] = Cr * b2i + Ci * b2r;
    p_dr[i] = dre; p_di[i] = dim;
    float eL = expf(dre * 4096.0f);
    float phL = dim * 4096.0f;
    p_lr[i] = eL * cosf(phL);
    p_li[i] = eL * sinf(phL);
  }
}

// ---- fused K1+K2: even blocks = hgemm(d), odd blocks = kc(d). --------------
// kc blocks are pure VALU/shuffle and co-schedule with hgemm's MFMA blocks on
// the same CUs (separate pipes, m114) -> kc time is hidden. One launch.
// hgemm: VLD double-buffered (gen(kt+1) VALU overlaps MFMA of kt); occupancy
// is 2 blocks/CU by 64KB LDS either way (grid-bound before).
__global__ __launch_bounds__(256) void k_hk(
    const ushort_t* __restrict__ u_bf,
    const float* __restrict__ p_ar, const float* __restrict__ p_ai,
    const float* __restrict__ p_wr, const float* __restrict__ p_wi,
    const float* __restrict__ p_dr, const float* __restrict__ p_di,
    const float* __restrict__ Dvec,
    float2* __restrict__ Hbuf, ushort_t* __restrict__ Kbuf) {
  __shared__ ushort_t VLD[2][128][128];
  int bid = blockIdx.x;
  int d = bid >> 1;
  int tid = threadIdx.x;

  if (bid & 1) {
    // ================= kc: kernel tail Kbuf[d][x] = K[3584+x] ===============
    int lane = tid & 63;          // state n
    int x0 = (tid >> 6) * 128;    // wave's x-range base
    int i = d * 64 + lane;
    float ar = p_ar[i], ai = p_ai[i];
    float wr = p_wr[i], wi = p_wi[i];
    float Dd = Dvec[d];
    f2 e = cexp(p_dr[i], p_di[i], (float)(3584 + x0));
    float zr = wr * e.x - wi * e.y;
    float zi = wr * e.y + wi * e.x;
    for (int bb = 0; bb < 8; ++bb) {
      float s[16];
#pragma unroll
      for (int j = 0; j < 16; ++j) {
        s[j] = zr;
        float tr = zr * ar - zi * ai;
        zi = zr * ai + zi * ar;
        zr = tr;
      }
      float out = 0.f;
#pragma unroll
      for (int j = 0; j < 16; ++j) {
        float r = s[j];
#pragma unroll
        for (int off = 1; off < 64; off <<= 1) r += __shfl_xor(r, off, 64);
        if (lane == j) out = r;   // cndmask select: value j lands in lane j
      }
      if (lane < 16) {
        int x = x0 + bb * 16 + lane;
        Kbuf[d * 512 + x] = f2bf(x == 511 ? out + Dd : out);
      }
    }
    return;
  }

  // ================= hgemm: H sums via MFMA =================================
  int wv = tid >> 6, lane = tid & 63;
  int wm = wv >> 1, wn = wv & 1;
  int lrow = lane & 15, quad = lane >> 4;

  int m = tid & 127, chalf = tid >> 7;
  int nn = m >> 1, pp = m & 1;
  float ar = p_ar[d * 64 + nn], ai = p_ai[d * 64 + nn];
  float dr = p_dr[d * 64 + nn], di = p_di[d * 64 + nn];

  f32x4 acc[4][4];
#pragma unroll
  for (int mt = 0; mt < 4; ++mt)
#pragma unroll
    for (int nt = 0; nt < 4; ++nt) acc[mt][nt] = (f32x4){0.f, 0.f, 0.f, 0.f};

  auto gen = [&](int kt, int bs) {
    f2 z = cexp(dr, di, (float)(kt * 128 + chalf * 64));
#pragma unroll
    for (int g8 = 0; g8 < 8; ++g8) {
      ushort_t vals[8];
#pragma unroll
      for (int e = 0; e < 8; ++e) {
        vals[e] = f2bf(pp ? z.y : z.x);
        float zr = z.x * ar - z.y * ai;
        z.y = z.x * ai + z.y * ar;
        z.x = zr;
      }
      int g = (chalf * 64 + g8 * 8) >> 3;
      int gph = g ^ (m & 7);
      uint4 pk;
      pk.x = (uint_t)vals[0] | ((uint_t)vals[1] << 16);
      pk.y = (uint_t)vals[2] | ((uint_t)vals[3] << 16);
      pk.z = (uint_t)vals[4] | ((uint_t)vals[5] << 16);
      pk.w = (uint_t)vals[6] | ((uint_t)vals[7] << 16);
      *(uint4*)&VLD[bs][m][gph << 3] = pk;
    }
  };

  gen(0, 0);
  __syncthreads();
  for (int kt = 0; kt < 4; ++kt) {
    int cur = kt & 1;
    if (kt < 3) gen(kt + 1, cur ^ 1);   // VALU gen overlaps MFMA below
#pragma unroll
    for (int kb = 0; kb < 4; ++kb) {
      int kbase = kb * 32 + quad * 8;
      short8 af[4], bf[4];
#pragma unroll
      for (int mt = 0; mt < 4; ++mt) {
        int mrow = wm * 64 + mt * 16 + lrow;
        int gph = (kbase >> 3) ^ (mrow & 7);
        af[mt] = *(const short8*)&VLD[cur][mrow][gph << 3];
      }
#pragma unroll
      for (int nt = 0; nt < 4; ++nt) {
        int col = wn * 64 + nt * 16 + lrow;
        int b = col >> 3, c = col & 7;
        bf[nt] = *(const short8*)(u_bf + (size_t)(b * 512 + d) * 4096 + c * 512 + kt * 128 + kbase);
      }
#pragma unroll
      for (int mt = 0; mt < 4; ++mt)
#pragma unroll
        for (int nt = 0; nt < 4; ++nt)
          acc[mt][nt] = __builtin_amdgcn_mfma_f32_16x16x32_bf16(af[mt], bf[nt], acc[mt][nt], 0, 0, 0);
    }
    __syncthreads();   // gen(kt+1) complete + reads of cur done
  }
#pragma unroll
  for (int mt = 0; mt < 4; ++mt) {
#pragma unroll
    for (int nt = 0; nt < 4; ++nt) {
      int col = wn * 64 + nt * 16 + lrow;
      int b = col >> 3, c = col & 7;
      int m0 = wm * 64 + mt * 16 + quad * 4;
      int n0 = m0 >> 1;
      float4 v = {acc[mt][nt][0], acc[mt][nt][1], acc[mt][nt][2], acc[mt][nt][3]};
      *(float4*)((float*)(Hbuf + ((size_t)((b * 8 + c) * 512 + d)) * 64 + n0)) = v;
    }
  }
}

// ---- K3: seeds. s[c] = A^((7-c)S) * F[cS-1], F excl own chunk. --------------
__global__ __launch_bounds__(256) void k_seedpack(
    const float* __restrict__ p_dr, const float* __restrict__ p_di,
    const float2* __restrict__ Hbuf, ushort_t* __restrict__ seedB) {
  __shared__ ushort_t tile[128 * 128];
  int d = blockIdx.x;
  int tid = threadIdx.x;
  int n = tid >> 2;      // 0..63
  int bq = tid & 3;
  float dr = p_dr[d * 64 + n], di = p_di[d * 64 + n];
  f2 AS = cexp(dr, di, 512.0f);
  f2 R[8];
  R[0] = (f2){1.f, 0.f};
#pragma unroll
  for (int c = 1; c < 8; ++c)
    R[c] = (f2){R[c-1].x * AS.x - R[c-1].y * AS.y, R[c-1].x * AS.y + R[c-1].y * AS.x};
  for (int bb = 0; bb < 4; ++bb) {
    int b = bq * 4 + bb;
    f2 G = {0.f, 0.f};
#pragma unroll
    for (int c = 0; c < 8; ++c) {
      f2 T = R[7 - c];
      float sr = T.x * G.x - T.y * G.y;
      float si = T.x * G.y + T.y * G.x;
      int col = b * 8 + c;
      tile[col * 128 + 2 * n]     = f2bf(sr);
      tile[col * 128 + 2 * n + 1] = f2bf(si);
      float2 h = Hbuf[((size_t)((b * 8 + c) * 512 + d)) * 64 + n];
      G.x += R[c].x * h.x - R[c].y * h.y;
      G.y += R[c].x * h.y + R[c].y * h.x;
    }
  }
  __syncthreads();
  const uint4* src = (const uint4*)tile;
  uint4* dst = (uint4*)(seedB + (size_t)d * 16384);
  for (int k = tid; k < 2048; k += 256) dst[k] = src[k];
}

// ---- K4: per-d Toeplitz + seed GEMM (MFMA), writes yraw (d,b,l) bf16 --------
// 1D grid 2048: id -> d = ((id>>5)<<3)|(id&7), t0 = ((id>>3)&3)*128.
// (4 tq-blocks of a d are 8 apart and id%8==d%8 -> same XCD -> u-slice L2 reuse)
#define KRN 1048
__global__ __launch_bounds__(256) void k_conv(
    const ushort_t* __restrict__ u_bf, const ushort_t* __restrict__ Kbuf,
    const ushort_t* __restrict__ seedB,
    const float* __restrict__ p_ar, const float* __restrict__ p_ai,
    const float* __restrict__ p_wr, const float* __restrict__ p_wi,
    const float* __restrict__ p_dr, const float* __restrict__ p_di,
    ushort_t* __restrict__ yraw) {
  __shared__ ushort_t KRc[8][KRN];
  __shared__ ushort_t PLD[128][136];
  int id = blockIdx.x;
  int d = ((id >> 5) << 3) | (id & 7);
  int t0 = ((id >> 3) & 3) * 128;
  int tid = threadIdx.x;

  for (int e = tid; e < 8 * KRN; e += 256) {
    int r = e / KRN, x = e - r * KRN;
    int y = x + r;
    KRc[r][x] = (y < 512) ? Kbuf[d * 512 + y] : (ushort_t)0;
  }
  {
    int n = tid & 63, mh = tid >> 6;
    int i = d * 64 + n;
    float ar = p_ar[i], ai = p_ai[i];
    float wr = p_wr[i], wi = p_wi[i];
    int mtop = mh * 32 + 31;
    f2 E = cexp(p_dr[i], p_di[i], (float)(511 - t0 - mtop));
    float zr = wr * E.x - wi * E.y;
    float zi = wr * E.y + wi * E.x;
    for (int m = mtop; m >= mh * 32; --m) {
      PLD[m][2 * n]     = f2bf(zr);
      PLD[m][2 * n + 1] = f2bf(-zi);
      float tr = zr * ar - zi * ai;
      zi = zr * ai + zi * ar;
      zr = tr;
    }
  }
  __syncthreads();

  int wv = tid >> 6, lane = tid & 63;
  int wm = wv >> 1, wn = wv & 1;
  int lrow = lane & 15, quad = lane >> 4;
  f32x4 acc[4][4];
#pragma unroll
  for (int mt = 0; mt < 4; ++mt)
#pragma unroll
    for (int nt = 0; nt < 4; ++nt) acc[mt][nt] = (f32x4){0.f, 0.f, 0.f, 0.f};

  for (int kt = 0; kt < 16; ++kt) {
    int kbase = kt * 32 + quad * 8;
    short8 af[4], bf[4];
#pragma unroll
    for (int mt = 0; mt < 4; ++mt) {
      int mr = wm * 64 + mt * 16 + lrow;
      int idx = 511 - t0 - mr + kbase;
      int r = idx & 7, st = idx - r;
      af[mt] = *(const short8*)&KRc[r][st];
    }
#pragma unroll
    for (int nt = 0; nt < 4; ++nt) {
      int col = wn * 64 + nt * 16 + lrow;
      int b = col >> 3, c = col & 7;
      bf[nt] = *(const short8*)(u_bf + (size_t)(b * 512 + d) * 4096 + c * 512 + kbase);
    }
#pragma unroll
    for (int mt = 0; mt < 4; ++mt)
#pragma unroll
      for (int nt = 0; nt < 4; ++nt)
        acc[mt][nt] = __builtin_amdgcn_mfma_f32_16x16x32_bf16(af[mt], bf[nt], acc[mt][nt], 0, 0, 0);
  }
  for (int kt = 0; kt < 4; ++kt) {
    int k2 = kt * 32 + quad * 8;
    short8 af[4], bf[4];
#pragma unroll
    for (int mt = 0; mt < 4; ++mt)
      af[mt] = *(const short8*)&PLD[wm * 64 + mt * 16 + lrow][k2];
#pragma unroll
    for (int nt = 0; nt < 4; ++nt) {
      int col = wn * 64 + nt * 16 + lrow;
      bf[nt] = *(const short8*)(seedB + (size_t)d * 16384 + col * 128 + k2);
    }
#pragma unroll
    for (int mt = 0; mt < 4; ++mt)
#pragma unroll
      for (int nt = 0; nt < 4; ++nt)
        acc[mt][nt] = __builtin_amdgcn_mfma_f32_16x16x32_bf16(af[mt], bf[nt], acc[mt][nt], 0, 0, 0);
  }

#pragma unroll
  for (int mt = 0; mt < 4; ++mt) {
#pragma unroll
    for (int nt = 0; nt < 4; ++nt) {
      int col = wn * 64 + nt * 16 + lrow;
      int b = col >> 3, c = col & 7;
      int tau = t0 + wm * 64 + mt * 16 + quad * 4;
      uint_t lo = (uint_t)f2bf(acc[mt][nt][0]) | ((uint_t)f2bf(acc[mt][nt][1]) << 16);
      uint_t hi = (uint_t)f2bf(acc[mt][nt][2]) | ((uint_t)f2bf(acc[mt][nt][3]) << 16);
      uint2 vv = {lo, hi};
      *(uint2*)(yraw + (size_t)d * 65536 + b * 4096 + c * 512 + tau) = vv;
    }
  }
}

// ---- K5: exact gelu + transpose: yraw (d,b,l) -> yg (b,l,d) bf16 ------------
// (D*u already folded into conv diagonal)
__global__ __launch_bounds__(256) void k_tg(
    const ushort_t* __restrict__ yraw, ushort_t* __restrict__ yg) {
  __shared__ ushort_t tile[64][72];
  int blk = blockIdx.x;
  int b = blk >> 9, dg = (blk >> 6) & 7, lg = blk & 63;
  int d0 = dg * 64, l0 = lg * 64;
  int tid = threadIdx.x;
  int dd = tid >> 2, lc = (tid & 3) * 16;

  const ushort_t* yp = yraw + (size_t)(d0 + dd) * 65536 + b * 4096 + l0 + lc;
  uint4 A0 = *(const uint4*)yp;
  uint4 A1 = *(const uint4*)(yp + 8);
  uint_t w[8] = {A0.x, A0.y, A0.z, A0.w, A1.x, A1.y, A1.z, A1.w};
#pragma unroll
  for (int i2 = 0; i2 < 16; ++i2) {
    ushort_t bits = (i2 & 1) ? (ushort_t)(w[i2 >> 1] >> 16) : (ushort_t)(w[i2 >> 1] & 0xffff);
    float y = bf2f(bits);
    float g = 0.5f * y * (1.0f + erff(y * 0.70710678118654752f));
    int row = lc + i2;
    int col = (dd + ((row >> 3) & 7) * 8) & 63;
    tile[row][col] = f2bf(g);
  }
  __syncthreads();
  int lr = tid >> 2, dc = (tid & 3) * 16;
  int rot = ((lr >> 3) & 7) * 8;
  int o1 = (dc + rot) & 63;
  int o2 = (dc + 8 + rot) & 63;
  uint4 v1 = *(const uint4*)&tile[lr][o1];
  uint4 v2 = *(const uint4*)&tile[lr][o2];
  ushort_t* og = yg + (size_t)b * (4096 * 512) + (size_t)(l0 + lr) * 512 + d0 + dc;
  *(uint4*)og = v1;
  *(uint4*)(og + 8) = v2;
}

// ---- 1x1 conv (512->1024) + bias + GLU + sum-over-L, fused ------------------
// 1D grid 4096: id -> p=id>>8, m=(id>>5)&7, q=id&31; n0=(p*32+q)*128, mp0=m*64.
// id%8==q%8 -> all 8 m-blocks of an n-tile on one XCD (yg L2 reuse).
// R5 form (best measured: 106-107us): single-buffer + global_load_lds staging,
// linear LDS dest + pre-swizzled global source (rule #21), swizzled reads,
// conflict-free, 32KB LDS. Occupancy is AGPR-bound (84 VGPR + 64 acc = 148 ->
// 3 blocks/CU); explicit dbuf REGRESSED (R6: 133us) - do not re-add.
__global__ __launch_bounds__(256) void k_gemm(
    const ushort_t* __restrict__ wbf, const ushort_t* __restrict__ yg,
    const float* __restrict__ b_out, float* __restrict__ pooled) {
  __shared__ ushort_t lwa[64][64];
  __shared__ ushort_t lwg[64][64];
  __shared__ ushort_t ly[128][64];
  int tid = threadIdx.x;
  int id = blockIdx.x;
  int p = id >> 8, m = (id >> 5) & 7, q = id & 31;
  int mp0 = m * 64;
  int n0 = (p * 32 + q) * 128;
  int b = n0 >> 12;
  int wv = tid >> 6, lane = tid & 63;
  int mh = wv >> 1, nh = wv & 1;
  int lrow = lane & 15, quad = lane >> 4;
  f32x4 accA[2][4], accG[2][4];
#pragma unroll
  for (int mt = 0; mt < 2; ++mt)
#pragma unroll
    for (int nt = 0; nt < 4; ++nt) {
      accA[mt][nt] = (f32x4){0.f, 0.f, 0.f, 0.f};
      accG[mt][nt] = (f32x4){0.f, 0.f, 0.f, 0.f};
    }

  // staging geometry: each gload16 covers 8 rows (1KB). lane c -> row sub=c>>3,
  // lds granule c&7; source granule (c&7)^(sub&7) [8-row groups keep row&7==sub&7]
  int sub = lane >> 3;
  int gsw = ((lane & 7) ^ (sub & 7)) * 8;   // pre-swizzled source col (ushorts)
  const ushort_t* gA0 = wbf + (size_t)(mp0 + wv * 16 + sub) * 512 + gsw;
  const ushort_t* gA1 = gA0 + 8 * 512;
  const ushort_t* gG0 = gA0 + (size_t)512 * 512;
  const ushort_t* gG1 = gA1 + (size_t)512 * 512;
  const ushort_t* gY0 = yg + (size_t)(n0 + wv * 32 + sub) * 512 + gsw;
  const ushort_t* gY1 = gY0 + 8 * 512;
  const ushort_t* gY2 = gY0 + 16 * 512;
  const ushort_t* gY3 = gY0 + 24 * 512;
  ushort_t* lA0 = &lwa[wv * 16][0];
  ushort_t* lA1 = &lwa[wv * 16 + 8][0];
  ushort_t* lG0 = &lwg[wv * 16][0];
  ushort_t* lG1 = &lwg[wv * 16 + 8][0];
  ushort_t* lY0 = &ly[wv * 32][0];
  ushort_t* lY1 = &ly[wv * 32 + 8][0];
  ushort_t* lY2 = &ly[wv * 32 + 16][0];
  ushort_t* lY3 = &ly[wv * 32 + 24][0];

  for (int kc = 0; kc < 8; ++kc) {
    int off = kc * 64;
    gload16(gA0 + off, lA0);
    gload16(gA1 + off, lA1);
    gload16(gG0 + off, lG0);
    gload16(gG1 + off, lG1);
    gload16(gY0 + off, lY0);
    gload16(gY1 + off, lY1);
    gload16(gY2 + off, lY2);
    gload16(gY3 + off, lY3);
    __syncthreads();
#pragma unroll
    for (int kb = 0; kb < 2; ++kb) {
      int kg = kb * 4 + quad;   // granule index of ko
      short8 bfv[4], af[2], gf[2];
#pragma unroll
      for (int nt = 0; nt < 4; ++nt) {
        int row = nh * 64 + nt * 16 + lrow;
        bfv[nt] = *(const short8*)&ly[row][(kg ^ (row & 7)) << 3];
      }
#pragma unroll
      for (int mt = 0; mt < 2; ++mt) {
        int row = mh * 32 + mt * 16 + lrow;
        af[mt] = *(const short8*)&lwa[row][(kg ^ (row & 7)) << 3];
        gf[mt] = *(const short8*)&lwg[row][(kg ^ (row & 7)) << 3];
      }
#pragma unroll
      for (int mt = 0; mt < 2; ++mt)
#pragma unroll
        for (int nt = 0; nt < 4; ++nt) {
          accA[mt][nt] = __builtin_amdgcn_mfma_f32_16x16x32_bf16(af[mt], bfv[nt], accA[mt][nt], 0, 0, 0);
          accG[mt][nt] = __builtin_amdgcn_mfma_f32_16x16x32_bf16(gf[mt], bfv[nt], accG[mt][nt], 0, 0, 0);
        }
    }
    __syncthreads();   // all reads done before next tile's DMA overwrites
  }
#pragma unroll
  for (int mt = 0; mt < 2; ++mt) {
#pragma unroll
    for (int reg = 0; reg < 4; ++reg) {
      int olocal = mh * 32 + mt * 16 + quad * 4 + reg;
      float ba = b_out[mp0 + olocal];
      float bg = b_out[512 + mp0 + olocal];
      float h = 0.f;
#pragma unroll
      for (int nt = 0; nt < 4; ++nt) {
        float a = accA[mt][nt][reg] + ba;
        float gv = accG[mt][nt][reg] + bg;
        h += a / (1.0f + __expf(-gv));
      }
#pragma unroll
      for (int off = 1; off < 16; off <<= 1) h += __shfl_xor(h, off, 16);
      if (lrow == 0) atomicAdd(&pooled[b * 512 + mp0 + olocal], h);
    }
  }
}

// ---- decoder ----------------------------------------------------------------
__global__ void k_final(const float* __restrict__ pooled, const float* __restrict__ W_dec,
                        const float* __restrict__ b_dec, float* __restrict__ out) {
  int b = blockIdx.x;
  int lane = threadIdx.x;
  float s = 0.f;
#pragma unroll
  for (int j = 0; j < 8; ++j) s += pooled[b * 512 + lane + 64 * j] * W_dec[lane + 64 * j];
#pragma unroll
  for (int off = 1; off < 64; off <<= 1) s += __shfl_xor(s, off, 64);
  if (lane == 0) out[b] = s * (1.0f / 4096.0f) + b_dec[0];
}

extern "C" void kernel_launch(void* const* d_in, const int* in_sizes, int n_in,
                              void* d_out, int out_size, void* d_ws, size_t ws_size,
                              hipStream_t stream) {
  const float* u          = (const float*)d_in[0];
  const float* log_dt     = (const float*)d_in[1];
  const float* log_A_real = (const float*)d_in[2];
  const float* A_imag     = (const float*)d_in[3];
  const float* B_re       = (const float*)d_in[4];
  const float* B_im       = (const float*)d_in[5];
  const float* C_re       = (const float*)d_in[6];
  const float* C_im       = (const float*)d_in[7];
  const float* Dv         = (const float*)d_in[8];
  const float* W_out      = (const float*)d_in[9];
  const float* b_out      = (const float*)d_in[10];
  const float* W_dec      = (const float*)d_in[11];
  const float* b_dec      = (const float*)d_in[12];

  float* ws = (float*)d_ws;
  float* p_ar = ws;
  float* p_ai = ws + 32768;
  float* p_wr = ws + 65536;
  float* p_wi = ws + 98304;
  float* p_dr = ws + 131072;
  float* p_di = ws + 163840;
  float* p_lr = ws + 196608;
  float* p_li = ws + 229376;
  float* pooled = (float*)((char*)d_ws + UOFF_POOLED);
  ushort_t* wbf   = (ushort_t*)((char*)d_ws + UOFF_WBF);
  ushort_t* u_bf  = (ushort_t*)((char*)d_ws + UOFF_UBF);
  ushort_t* yg    = (ushort_t*)((char*)d_ws + UOFF_UBF);    // alias: reused after k_conv
  ushort_t* yraw  = (ushort_t*)((char*)d_ws + UOFF_YRAW);
  float2*   Hbuf  = (float2*)((char*)d_ws + UOFF_YRAW);     // alias: dead before k_conv writes
  ushort_t* seedB = (ushort_t*)((char*)d_ws + UOFF_SEEDB);
  ushort_t* Kbuf  = (ushort_t*)((char*)d_ws + UOFF_KBUF);

  hipMemsetAsync(pooled, 0, 16 * 512 * sizeof(float), stream);
  k_prep<<<18560, 256, 0, stream>>>(u, u_bf, W_out, wbf,
                                    log_dt, log_A_real, A_imag, B_re, B_im, C_re, C_im,
                                    p_ar, p_ai, p_wr, p_wi, p_dr, p_di, p_lr, p_li);
  k_hk<<<1024, 256, 0, stream>>>(u_bf, p_ar, p_ai, p_wr, p_wi, p_dr, p_di, Dv,
                                 Hbuf, Kbuf);
  k_seedpack<<<512, 256, 0, stream>>>(p_dr, p_di, Hbuf, seedB);
  k_conv<<<2048, 256, 0, stream>>>(u_bf, Kbuf, seedB,
                                   p_ar, p_ai, p_wr, p_wi, p_dr, p_di, yraw);
  k_tg<<<8192, 256, 0, stream>>>(yraw, yg);
  k_gemm<<<4096, 256, 0, stream>>>(wbf, yg, b_out, pooled);
  k_final<<<16, 64, 0, stream>>>(pooled, W_dec, b_dec, (float*)d_out);
}

// Round 9
// 489.277 us; speedup vs baseline: 1.0706x; 1.0159x over previous
//
#include <hip/hip_runtime.h>

// MiniS4D: B=16, D=512, N=64 states, L=4096, C=8 chunks of S=512.
// Pipeline (6 launches): k_prep (params+wcvt+ucvt) -> k_hk (hgemm+seedpack
// fused on even blocks, kc on odd blocks) -> k_conv -> k_tg -> k_gemm -> k_final
// ws byte layout (153.6 MB):
//   [0)          params: p_ar,p_ai,p_wr,p_wi,p_dr,p_di,p_lr,p_li (8 x 131072)
//   [1048576)    pooled 32KB
//   [1081344)    wbf 1MB
//   [2129920)    UBF  u_bf bf16 67.1MB   (ALIAS: yg reuses this region after k_conv)
//   [69238784)   YRAW bf16 67.1MB        (Hbuf eliminated in R9: H passes via LDS)
//   [136347648)  seedB bf16 16.8MB
//   [153124864)  Kbuf bf16 0.52MB  -> end 153649152

#define UOFF_POOLED 1048576
#define UOFF_WBF    1081344
#define UOFF_UBF    2129920
#define UOFF_YRAW   69238784
#define UOFF_SEEDB  136347648
#define UOFF_KBUF   153124864

typedef __attribute__((ext_vector_type(8))) short short8;
typedef __attribute__((ext_vector_type(4))) float f32x4;
typedef __attribute__((ext_vector_type(2))) float f2;
typedef unsigned short ushort_t;
typedef unsigned int uint_t;

__device__ __forceinline__ ushort_t f2bf(float f) {
  uint_t u = __float_as_uint(f);
  u = (u + 0x7FFF + ((u >> 16) & 1)) >> 16;  // RNE
  return (ushort_t)u;
}
__device__ __forceinline__ float bf2f(ushort_t v) {
  return __uint_as_float(((uint_t)v) << 16);
}

// async global->LDS 16B: linear LDS dest (wave-uniform base + lane*16)
__device__ __forceinline__ void gload16(const ushort_t* g, ushort_t* l) {
  __builtin_amdgcn_global_load_lds(
      (const __attribute__((address_space(1))) void*)g,
      (__attribute__((address_space(3))) void*)l, 16, 0, 0);
}

// exp(dr*t) * cis(di*t)
__device__ __forceinline__ f2 cexp(float dr, float di, float t) {
  float e = expf(dr * t);
  float ph = di * t;
  return (f2){e * cosf(ph), e * sinf(ph)};
}

// ---- fused prep: u->bf16 (16384 blk) | W_out->bf16 (2048 blk) | params (128)
__global__ __launch_bounds__(256) void k_prep(
    const float* __restrict__ u, ushort_t* __restrict__ u_bf,
    const float* __restrict__ W_out, ushort_t* __restrict__ wbf,
    const float* __restrict__ log_dt, const float* __restrict__ log_A_real,
    const float* __restrict__ A_imag,
    const float* __restrict__ B_re, const float* __restrict__ B_im,
    const float* __restrict__ C_re, const float* __restrict__ C_im,
    float* __restrict__ p_ar, float* __restrict__ p_ai,
    float* __restrict__ p_wr, float* __restrict__ p_wi,
    float* __restrict__ p_dr, float* __restrict__ p_di,
    float* __restrict__ p_lr, float* __restrict__ p_li) {
  int bid = blockIdx.x;
  if (bid < 16384) {                       // ---- u fp32 -> bf16, 8 elems/thread
    size_t i = (size_t)bid * 256 + threadIdx.x;
    const float4* p = (const float4*)u + 2 * i;
    float4 a = p[0], b = p[1];
    uint4 v;
    v.x = (uint_t)f2bf(a.x) | ((uint_t)f2bf(a.y) << 16);
    v.y = (uint_t)f2bf(a.z) | ((uint_t)f2bf(a.w) << 16);
    v.z = (uint_t)f2bf(b.x) | ((uint_t)f2bf(b.y) << 16);
    v.w = (uint_t)f2bf(b.z) | ((uint_t)f2bf(b.w) << 16);
    ((uint4*)u_bf)[i] = v;
  } else if (bid < 16384 + 2048) {         // ---- W_out fp32 -> bf16
    int i = (bid - 16384) * 256 + threadIdx.x;
    if (i < 1024 * 512) wbf[i] = f2bf(W_out[i]);
  } else {                                 // ---- derived SSM params
    int i = (bid - 18432) * 256 + threadIdx.x;   // 0..32767
    int d = i >> 6;
    float dt  = expf(log_dt[d]);
    float Are = -expf(log_A_real[i]);
    float Aim = A_imag[i];
    float dre = dt * Are, dim = dt * Aim;
    float em  = expf(dre);
    float abr = em * cosf(dim);
    float abi = em * sinf(dim);
    float nr = abr - 1.0f, ni = abi;
    float inv = 1.0f / (Are * Are + Aim * Aim);
    float br = (nr * Are + ni * Aim) * inv;
    float bi = (ni * Are - nr * Aim) * inv;
    float Br = B_re[i], Bi = B_im[i];
    float b2r = br * Br - bi * Bi;
    float b2i = br * Bi + bi * Br;
    float Cr = C_re[i], Ci = C_im[i];
    p_ar[i] = abr; p_ai[i] = abi;
    p_wr[i] = Cr * b2r - Ci * b2i;
    p_wi[i] = Cr * b2i + Ci * b2r;
    p_dr[i] = dre; p_di[i] = dim;
    float eL = expf(dre * 4096.0f);
    float phL = dim * 4096.0f;
    p_lr[i] = eL * cosf(phL);
    p_li[i] = eL * sinf(phL);
  }
}

// ---- fused K1+K2+K3: even blocks = hgemm(d)+seedpack(d), odd = kc(d). ------
// seedpack[d] depends only on hgemm block d's H output -> H passes through LDS
// (reusing VLD's 64KB: first 32KB = float2 H[col][n], second 32KB = bf16 tile),
// never touching HBM. kc blocks (pure VALU/shuffle) co-schedule with hgemm's
// MFMA blocks on the same CUs (separate pipes, m114).
__global__ __launch_bounds__(256) void k_hk(
    const ushort_t* __restrict__ u_bf,
    const float* __restrict__ p_ar, const float* __restrict__ p_ai,
    const float* __restrict__ p_wr, const float* __restrict__ p_wi,
    const float* __restrict__ p_dr, const float* __restrict__ p_di,
    const float* __restrict__ Dvec,
    ushort_t* __restrict__ seedB, ushort_t* __restrict__ Kbuf) {
  __shared__ ushort_t VLD[2][128][128];   // 64KB; aliased post-loop (see below)
  int bid = blockIdx.x;
  int d = bid >> 1;
  int tid = threadIdx.x;

  if (bid & 1) {
    // ================= kc: kernel tail Kbuf[d][x] = K[3584+x] ===============
    int lane = tid & 63;          // state n
    int x0 = (tid >> 6) * 128;    // wave's x-range base
    int i = d * 64 + lane;
    float ar = p_ar[i], ai = p_ai[i];
    float wr = p_wr[i], wi = p_wi[i];
    float Dd = Dvec[d];
    f2 e = cexp(p_dr[i], p_di[i], (float)(3584 + x0));
    float zr = wr * e.x - wi * e.y;
    float zi = wr * e.y + wi * e.x;
    for (int bb = 0; bb < 8; ++bb) {
      float s[16];
#pragma unroll
      for (int j = 0; j < 16; ++j) {
        s[j] = zr;
        float tr = zr * ar - zi * ai;
        zi = zr * ai + zi * ar;
        zr = tr;
      }
      float out = 0.f;
#pragma unroll
      for (int j = 0; j < 16; ++j) {
        float r = s[j];
#pragma unroll
        for (int off = 1; off < 64; off <<= 1) r += __shfl_xor(r, off, 64);
        if (lane == j) out = r;   // cndmask select: value j lands in lane j
      }
      if (lane < 16) {
        int x = x0 + bb * 16 + lane;
        Kbuf[d * 512 + x] = f2bf(x == 511 ? out + Dd : out);
      }
    }
    return;
  }

  // ================= hgemm: H sums via MFMA =================================
  int wv = tid >> 6, lane = tid & 63;
  int wm = wv >> 1, wn = wv & 1;
  int lrow = lane & 15, quad = lane >> 4;

  int m = tid & 127, chalf = tid >> 7;
  int nn = m >> 1, pp = m & 1;
  float ar = p_ar[d * 64 + nn], ai = p_ai[d * 64 + nn];
  float dr = p_dr[d * 64 + nn], di = p_di[d * 64 + nn];

  f32x4 acc[4][4];
#pragma unroll
  for (int mt = 0; mt < 4; ++mt)
#pragma unroll
    for (int nt = 0; nt < 4; ++nt) acc[mt][nt] = (f32x4){0.f, 0.f, 0.f, 0.f};

  auto gen = [&](int kt, int bs) {
    f2 z = cexp(dr, di, (float)(kt * 128 + chalf * 64));
#pragma unroll
    for (int g8 = 0; g8 < 8; ++g8) {
      ushort_t vals[8];
#pragma unroll
      for (int e = 0; e < 8; ++e) {
        vals[e] = f2bf(pp ? z.y : z.x);
        float zr = z.x * ar - z.y * ai;
        z.y = z.x * ai + z.y * ar;
        z.x = zr;
      }
      int g = (chalf * 64 + g8 * 8) >> 3;
      int gph = g ^ (m & 7);
      uint4 pk;
      pk.x = (uint_t)vals[0] | ((uint_t)vals[1] << 16);
      pk.y = (uint_t)vals[2] | ((uint_t)vals[3] << 16);
      pk.z = (uint_t)vals[4] | ((uint_t)vals[5] << 16);
      pk.w = (uint_t)vals[6] | ((uint_t)vals[7] << 16);
      *(uint4*)&VLD[bs][m][gph << 3] = pk;
    }
  };

  gen(0, 0);
  __syncthreads();
  for (int kt = 0; kt < 4; ++kt) {
    int cur = kt & 1;
    if (kt < 3) gen(kt + 1, cur ^ 1);   // VALU gen overlaps MFMA below
#pragma unroll
    for (int kb = 0; kb < 4; ++kb) {
      int kbase = kb * 32 + quad * 8;
      short8 af[4], bf[4];
#pragma unroll
      for (int mt = 0; mt < 4; ++mt) {
        int mrow = wm * 64 + mt * 16 + lrow;
        int gph = (kbase >> 3) ^ (mrow & 7);
        af[mt] = *(const short8*)&VLD[cur][mrow][gph << 3];
      }
#pragma unroll
      for (int nt = 0; nt < 4; ++nt) {
        int col = wn * 64 + nt * 16 + lrow;
        int b = col >> 3, c = col & 7;
        bf[nt] = *(const short8*)(u_bf + (size_t)(b * 512 + d) * 4096 + c * 512 + kt * 128 + kbase);
      }
#pragma unroll
      for (int mt = 0; mt < 4; ++mt)
#pragma unroll
        for (int nt = 0; nt < 4; ++nt)
          acc[mt][nt] = __builtin_amdgcn_mfma_f32_16x16x32_bf16(af[mt], bf[nt], acc[mt][nt], 0, 0, 0);
    }
    __syncthreads();   // gen(kt+1) complete + reads of cur done
  }

  // ---- H -> LDS (reuse VLD[0] as float2 Hl[col][n], 32KB) -------------------
  float2* Hl = (float2*)VLD;                       // 64 cols x 64 states
  ushort_t* tile = (ushort_t*)VLD + 16384;         // 32KB bf16 seed staging
#pragma unroll
  for (int mt = 0; mt < 4; ++mt) {
#pragma unroll
    for (int nt = 0; nt < 4; ++nt) {
      int col = wn * 64 + nt * 16 + lrow;
      int m0 = wm * 64 + mt * 16 + quad * 4;
      int n0 = m0 >> 1;                            // even (m0 multiple of 4)
      float4 v = {acc[mt][nt][0], acc[mt][nt][1], acc[mt][nt][2], acc[mt][nt][3]};
      *(float4*)&Hl[col * 64 + n0] = v;
    }
  }
  __syncthreads();

  // ---- seedpack(d): s[c] = A^((7-c)S) * F[cS-1], F excl own chunk ----------
  {
    int n = tid >> 2;      // 0..63
    int bq = tid & 3;
    float sdr = p_dr[d * 64 + n], sdi = p_di[d * 64 + n];
    f2 AS = cexp(sdr, sdi, 512.0f);
    f2 R[8];
    R[0] = (f2){1.f, 0.f};
#pragma unroll
    for (int c = 1; c < 8; ++c)
      R[c] = (f2){R[c-1].x * AS.x - R[c-1].y * AS.y, R[c-1].x * AS.y + R[c-1].y * AS.x};
    for (int bb = 0; bb < 4; ++bb) {
      int b = bq * 4 + bb;
      f2 G = {0.f, 0.f};
#pragma unroll
      for (int c = 0; c < 8; ++c) {
        f2 T = R[7 - c];
        float sr = T.x * G.x - T.y * G.y;
        float si = T.x * G.y + T.y * G.x;
        int col = b * 8 + c;
        tile[col * 128 + 2 * n]     = f2bf(sr);
        tile[col * 128 + 2 * n + 1] = f2bf(si);
        float2 h = Hl[(b * 8 + c) * 64 + n];
        G.x += R[c].x * h.x - R[c].y * h.y;
        G.y += R[c].x * h.y + R[c].y * h.x;
      }
    }
  }
  __syncthreads();
  {
    const uint4* src = (const uint4*)tile;
    uint4* dst = (uint4*)(seedB + (size_t)d * 16384);
    for (int k = tid; k < 2048; k += 256) dst[k] = src[k];
  }
}

// ---- K4: per-d Toeplitz + seed GEMM (MFMA), writes yraw (d,b,l) bf16 --------
// 1D grid 2048: id -> d = ((id>>5)<<3)|(id&7), t0 = ((id>>3)&3)*128.
// (4 tq-blocks of a d are 8 apart and id%8==d%8 -> same XCD -> u-slice L2 reuse)
#define KRN 1048
__global__ __launch_bounds__(256) void k_conv(
    const ushort_t* __restrict__ u_bf, const ushort_t* __restrict__ Kbuf,
    const ushort_t* __restrict__ seedB,
    const float* __restrict__ p_ar, const float* __restrict__ p_ai,
    const float* __restrict__ p_wr, const float* __restrict__ p_wi,
    const float* __restrict__ p_dr, const float* __restrict__ p_di,
    ushort_t* __restrict__ yraw) {
  __shared__ ushort_t KRc[8][KRN];
  __shared__ ushort_t PLD[128][136];
  int id = blockIdx.x;
  int d = ((id >> 5) << 3) | (id & 7);
  int t0 = ((id >> 3) & 3) * 128;
  int tid = threadIdx.x;

#pragma unroll
  for (int r = 0; r < 8; ++r)
    for (int x = tid; x < KRN; x += 256) {   // no integer division (was e/KRN)
      int y = x + r;
      KRc[r][x] = (y < 512) ? Kbuf[d * 512 + y] : (ushort_t)0;
    }
  {
    int n = tid & 63, mh = tid >> 6;
    int i = d * 64 + n;
    float ar = p_ar[i], ai = p_ai[i];
    float wr = p_wr[i], wi = p_wi[i];
    int mtop = mh * 32 + 31;
    f2 E = cexp(p_dr[i], p_di[i], (float)(511 - t0 - mtop));
    float zr = wr * E.x - wi * E.y;
    float zi = wr * E.y + wi * E.x;
    for (int m = mtop; m >= mh * 32; --m) {
      PLD[m][2 * n]     = f2bf(zr);
      PLD[m][2 * n + 1] = f2bf(-zi);
      float tr = zr * ar - zi * ai;
      zi = zr * ai + zi * ar;
      zr = tr;
    }
  }
  __syncthreads();

  int wv = tid >> 6, lane = tid & 63;
  int wm = wv >> 1, wn = wv & 1;
  int lrow = lane & 15, quad = lane >> 4;
  f32x4 acc[4][4];
#pragma unroll
  for (int mt = 0; mt < 4; ++mt)
#pragma unroll
    for (int nt = 0; nt < 4; ++nt) acc[mt][nt] = (f32x4){0.f, 0.f, 0.f, 0.f};

  for (int kt = 0; kt < 16; ++kt) {
    int kbase = kt * 32 + quad * 8;
    short8 af[4], bf[4];
#pragma unroll
    for (int mt = 0; mt < 4; ++mt) {
      int mr = wm * 64 + mt * 16 + lrow;
      int idx = 511 - t0 - mr + kbase;
      int r = idx & 7, st = idx - r;
      af[mt] = *(const short8*)&KRc[r][st];
    }
#pragma unroll
    for (int nt = 0; nt < 4; ++nt) {
      int col = wn * 64 + nt * 16 + lrow;
      int b = col >> 3, c = col & 7;
      bf[nt] = *(const short8*)(u_bf + (size_t)(b * 512 + d) * 4096 + c * 512 + kbase);
    }
#pragma unroll
    for (int mt = 0; mt < 4; ++mt)
#pragma unroll
      for (int nt = 0; nt < 4; ++nt)
        acc[mt][nt] = __builtin_amdgcn_mfma_f32_16x16x32_bf16(af[mt], bf[nt], acc[mt][nt], 0, 0, 0);
  }
  for (int kt = 0; kt < 4; ++kt) {
    int k2 = kt * 32 + quad * 8;
    short8 af[4], bf[4];
#pragma unroll
    for (int mt = 0; mt < 4; ++mt)
      af[mt] = *(const short8*)&PLD[wm * 64 + mt * 16 + lrow][k2];
#pragma unroll
    for (int nt = 0; nt < 4; ++nt) {
      int col = wn * 64 + nt * 16 + lrow;
      bf[nt] = *(const short8*)(seedB + (size_t)d * 16384 + col * 128 + k2);
    }
#pragma unroll
    for (int mt = 0; mt < 4; ++mt)
#pragma unroll
      for (int nt = 0; nt < 4; ++nt)
        acc[mt][nt] = __builtin_amdgcn_mfma_f32_16x16x32_bf16(af[mt], bf[nt], acc[mt][nt], 0, 0, 0);
  }

#pragma unroll
  for (int mt = 0; mt < 4; ++mt) {
#pragma unroll
    for (int nt = 0; nt < 4; ++nt) {
      int col = wn * 64 + nt * 16 + lrow;
      int b = col >> 3, c = col & 7;
      int tau = t0 + wm * 64 + mt * 16 + quad * 4;
      uint_t lo = (uint_t)f2bf(acc[mt][nt][0]) | ((uint_t)f2bf(acc[mt][nt][1]) << 16);
      uint_t hi = (uint_t)f2bf(acc[mt][nt][2]) | ((uint_t)f2bf(acc[mt][nt][3]) << 16);
      uint2 vv = {lo, hi};
      *(uint2*)(yraw + (size_t)d * 65536 + b * 4096 + c * 512 + tau) = vv;
    }
  }
}

// ---- K5: exact gelu + transpose: yraw (d,b,l) -> yg (b,l,d) bf16 ------------
// (D*u already folded into conv diagonal)
__global__ __launch_bounds__(256) void k_tg(
    const ushort_t* __restrict__ yraw, ushort_t* __restrict__ yg) {
  __shared__ ushort_t tile[64][72];
  int blk = blockIdx.x;
  int b = blk >> 9, dg = (blk >> 6) & 7, lg = blk & 63;
  int d0 = dg * 64, l0 = lg * 64;
  int tid = threadIdx.x;
  int dd = tid >> 2, lc = (tid & 3) * 16;

  const ushort_t* yp = yraw + (size_t)(d0 + dd) * 65536 + b * 4096 + l0 + lc;
  uint4 A0 = *(const uint4*)yp;
  uint4 A1 = *(const uint4*)(yp + 8);
  uint_t w[8] = {A0.x, A0.y, A0.z, A0.w, A1.x, A1.y, A1.z, A1.w};
#pragma unroll
  for (int i2 = 0; i2 < 16; ++i2) {
    ushort_t bits = (i2 & 1) ? (ushort_t)(w[i2 >> 1] >> 16) : (ushort_t)(w[i2 >> 1] & 0xffff);
    float y = bf2f(bits);
    float g = 0.5f * y * (1.0f + erff(y * 0.70710678118654752f));
    int row = lc + i2;
    int col = (dd + ((row >> 3) & 7) * 8) & 63;
    tile[row][col] = f2bf(g);
  }
  __syncthreads();
  int lr = tid >> 2, dc = (tid & 3) * 16;
  int rot = ((lr >> 3) & 7) * 8;
  int o1 = (dc + rot) & 63;
  int o2 = (dc + 8 + rot) & 63;
  uint4 v1 = *(const uint4*)&tile[lr][o1];
  uint4 v2 = *(const uint4*)&tile[lr][o2];
  ushort_t* og = yg + (size_t)b * (4096 * 512) + (size_t)(l0 + lr) * 512 + d0 + dc;
  *(uint4*)og = v1;
  *(uint4*)(og + 8) = v2;
}

// ---- 1x1 conv (512->1024) + bias + GLU + sum-over-L, fused ------------------
// 1D grid 4096: id -> p=id>>8, m=(id>>5)&7, q=id&31; n0=(p*32+q)*128, mp0=m*64.
// id%8==q%8 -> all 8 m-blocks of an n-tile on one XCD (yg L2 reuse).
// R5 form (best measured: 106-108us): single-buffer + global_load_lds staging,
// linear LDS dest + pre-swizzled global source (rule #21), swizzled reads,
// conflict-free, 32KB LDS. Occupancy is AGPR-bound (84 VGPR + 64 acc = 148 ->
// 3 blocks/CU); explicit dbuf REGRESSED (R6: 133us) - do not re-add.
__global__ __launch_bounds__(256) void k_gemm(
    const ushort_t* __restrict__ wbf, const ushort_t* __restrict__ yg,
    const float* __restrict__ b_out, float* __restrict__ pooled) {
  __shared__ ushort_t lwa[64][64];
  __shared__ ushort_t lwg[64][64];
  __shared__ ushort_t ly[128][64];
  int tid = threadIdx.x;
  int id = blockIdx.x;
  int p = id >> 8, m = (id >> 5) & 7, q = id & 31;
  int mp0 = m * 64;
  int n0 = (p * 32 + q) * 128;
  int b = n0 >> 12;
  int wv = tid >> 6, lane = tid & 63;
  int mh = wv >> 1, nh = wv & 1;
  int lrow = lane & 15, quad = lane >> 4;
  f32x4 accA[2][4], accG[2][4];
#pragma unroll
  for (int mt = 0; mt < 2; ++mt)
#pragma unroll
    for (int nt = 0; nt < 4; ++nt) {
      accA[mt][nt] = (f32x4){0.f, 0.f, 0.f, 0.f};
      accG[mt][nt] = (f32x4){0.f, 0.f, 0.f, 0.f};
    }

  // staging geometry: each gload16 covers 8 rows (1KB). lane c -> row sub=c>>3,
  // lds granule c&7; source granule (c&7)^(sub&7) [8-row groups keep row&7==sub&7]
  int sub = lane >> 3;
  int gsw = ((lane & 7) ^ (sub & 7)) * 8;   // pre-swizzled source col (ushorts)
  const ushort_t* gA0 = wbf + (size_t)(mp0 + wv * 16 + sub) * 512 + gsw;
  const ushort_t* gA1 = gA0 + 8 * 512;
  const ushort_t* gG0 = gA0 + (size_t)512 * 512;
  const ushort_t* gG1 = gA1 + (size_t)512 * 512;
  const ushort_t* gY0 = yg + (size_t)(n0 + wv * 32 + sub) * 512 + gsw;
  const ushort_t* gY1 = gY0 + 8 * 512;
  const ushort_t* gY2 = gY0 + 16 * 512;
  const ushort_t* gY3 = gY0 + 24 * 512;
  ushort_t* lA0 = &lwa[wv * 16][0];
  ushort_t* lA1 = &lwa[wv * 16 + 8][0];
  ushort_t* lG0 = &lwg[wv * 16][0];
  ushort_t* lG1 = &lwg[wv * 16 + 8][0];
  ushort_t* lY0 = &ly[wv * 32][0];
  ushort_t* lY1 = &ly[wv * 32 + 8][0];
  ushort_t* lY2 = &ly[wv * 32 + 16][0];
  ushort_t* lY3 = &ly[wv * 32 + 24][0];

  for (int kc = 0; kc < 8; ++kc) {
    int off = kc * 64;
    gload16(gA0 + off, lA0);
    gload16(gA1 + off, lA1);
    gload16(gG0 + off, lG0);
    gload16(gG1 + off, lG1);
    gload16(gY0 + off, lY0);
    gload16(gY1 + off, lY1);
    gload16(gY2 + off, lY2);
    gload16(gY3 + off, lY3);
    __syncthreads();
#pragma unroll
    for (int kb = 0; kb < 2; ++kb) {
      int kg = kb * 4 + quad;   // granule index of ko
      short8 bfv[4], af[2], gf[2];
#pragma unroll
      for (int nt = 0; nt < 4; ++nt) {
        int row = nh * 64 + nt * 16 + lrow;
        bfv[nt] = *(const short8*)&ly[row][(kg ^ (row & 7)) << 3];
      }
#pragma unroll
      for (int mt = 0; mt < 2; ++mt) {
        int row = mh * 32 + mt * 16 + lrow;
        af[mt] = *(const short8*)&lwa[row][(kg ^ (row & 7)) << 3];
        gf[mt] = *(const short8*)&lwg[row][(kg ^ (row & 7)) << 3];
      }
#pragma unroll
      for (int mt = 0; mt < 2; ++mt)
#pragma unroll
        for (int nt = 0; nt < 4; ++nt) {
          accA[mt][nt] = __builtin_amdgcn_mfma_f32_16x16x32_bf16(af[mt], bfv[nt], accA[mt][nt], 0, 0, 0);
          accG[mt][nt] = __builtin_amdgcn_mfma_f32_16x16x32_bf16(gf[mt], bfv[nt], accG[mt][nt], 0, 0, 0);
        }
    }
    __syncthreads();   // all reads done before next tile's DMA overwrites
  }
#pragma unroll
  for (int mt = 0; mt < 2; ++mt) {
#pragma unroll
    for (int reg = 0; reg < 4; ++reg) {
      int olocal = mh * 32 + mt * 16 + quad * 4 + reg;
      float ba = b_out[mp0 + olocal];
      float bg = b_out[512 + mp0 + olocal];
      float h = 0.f;
#pragma unroll
      for (int nt = 0; nt < 4; ++nt) {
        float a = accA[mt][nt][reg] + ba;
        float gv = accG[mt][nt][reg] + bg;
        h += a / (1.0f + __expf(-gv));
      }
#pragma unroll
      for (int off = 1; off < 16; off <<= 1) h += __shfl_xor(h, off, 16);
      if (lrow == 0) atomicAdd(&pooled[b * 512 + mp0 + olocal], h);
    }
  }
}

// ---- decoder ----------------------------------------------------------------
__global__ void k_final(const float* __restrict__ pooled, const float* __restrict__ W_dec,
                        const float* __restrict__ b_dec, float* __restrict__ out) {
  int b = blockIdx.x;
  int lane = threadIdx.x;
  float s = 0.f;
#pragma unroll
  for (int j = 0; j < 8; ++j) s += pooled[b * 512 + lane + 64 * j] * W_dec[lane + 64 * j];
#pragma unroll
  for (int off = 1; off < 64; off <<= 1) s += __shfl_xor(s, off, 64);
  if (lane == 0) out[b] = s * (1.0f / 4096.0f) + b_dec[0];
}

extern "C" void kernel_launch(void* const* d_in, const int* in_sizes, int n_in,
                              void* d_out, int out_size, void* d_ws, size_t ws_size,
                              hipStream_t stream) {
  const float* u          = (const float*)d_in[0];
  const float* log_dt     = (const float*)d_in[1];
  const float* log_A_real = (const float*)d_in[2];
  const float* A_imag     = (const float*)d_in[3];
  const float* B_re       = (const float*)d_in[4];
  const float* B_im       = (const float*)d_in[5];
  const float* C_re       = (const float*)d_in[6];
  const float* C_im       = (const float*)d_in[7];
  const float* Dv         = (const float*)d_in[8];
  const float* W_out      = (const float*)d_in[9];
  const float* b_out      = (const float*)d_in[10];
  const float* W_dec      = (const float*)d_in[11];
  const float* b_dec      = (const float*)d_in[12];

  float* ws = (float*)d_ws;
  float* p_ar = ws;
  float* p_ai = ws + 32768;
  float* p_wr = ws + 65536;
  float* p_wi = ws + 98304;
  float* p_dr = ws + 131072;
  float* p_di = ws + 163840;
  float* p_lr = ws + 196608;
  float* p_li = ws + 229376;
  float* pooled = (float*)((char*)d_ws + UOFF_POOLED);
  ushort_t* wbf   = (ushort_t*)((char*)d_ws + UOFF_WBF);
  ushort_t* u_bf  = (ushort_t*)((char*)d_ws + UOFF_UBF);
  ushort_t* yg    = (ushort_t*)((char*)d_ws + UOFF_UBF);    // alias: reused after k_conv
  ushort_t* yraw  = (ushort_t*)((char*)d_ws + UOFF_YRAW);
  ushort_t* seedB = (ushort_t*)((char*)d_ws + UOFF_SEEDB);
  ushort_t* Kbuf  = (ushort_t*)((char*)d_ws + UOFF_KBUF);

  hipMemsetAsync(pooled, 0, 16 * 512 * sizeof(float), stream);
  k_prep<<<18560, 256, 0, stream>>>(u, u_bf, W_out, wbf,
                                    log_dt, log_A_real, A_imag, B_re, B_im, C_re, C_im,
                                    p_ar, p_ai, p_wr, p_wi, p_dr, p_di, p_lr, p_li);
  k_hk<<<1024, 256, 0, stream>>>(u_bf, p_ar, p_ai, p_wr, p_wi, p_dr, p_di, Dv,
                                 seedB, Kbuf);
  k_conv<<<2048, 256, 0, stream>>>(u_bf, Kbuf, seedB,
                                   p_ar, p_ai, p_wr, p_wi, p_dr, p_di, yraw);
  k_tg<<<8192, 256, 0, stream>>>(yraw, yg);
  k_gemm<<<4096, 256, 0, stream>>>(wbf, yg, b_out, pooled);
  k_final<<<16, 64, 0, stream>>>(pooled, W_dec, b_dec, (float*)d_out);
}